// Round 1
// baseline (2613.407 us; speedup 1.0000x reference)
//
#include <hip/hip_runtime.h>
#include <math.h>

// ---- problem constants ----
#define S_LEN  2048
#define DMODEL 1024
#define NHEAD  16
#define BATCH  4
#define NROWS  (BATCH*S_LEN)   // 8192
#define DFF    4096
#define QKV_LD 3072            // fused q|k|v row stride

typedef __attribute__((ext_vector_type(4))) unsigned short us4;
typedef __attribute__((ext_vector_type(8))) unsigned short us8;
typedef __attribute__((ext_vector_type(8))) __bf16 bf16x8;
typedef __attribute__((ext_vector_type(4))) float f32x4;

static __device__ __forceinline__ unsigned short f2bf(float f) {
  unsigned int u = __builtin_bit_cast(unsigned int, f);
  u = (u + 0x7fffu + ((u >> 16) & 1u)) >> 16;
  return (unsigned short)u;
}
static __device__ __forceinline__ bf16x8 mk8(us4 a, us4 b) {
  us8 t;
  t[0]=a[0]; t[1]=a[1]; t[2]=a[2]; t[3]=a[3];
  t[4]=b[0]; t[5]=b[1]; t[6]=b[2]; t[7]=b[3];
  return __builtin_bit_cast(bf16x8, t);
}
#define GLD16(gp, lp) __builtin_amdgcn_global_load_lds( \
    (const __attribute__((address_space(1))) unsigned int*)(gp), \
    (__attribute__((address_space(3))) unsigned int*)(lp), 16, 0, 0)

// ---------------- LayerNorm: fp32 in -> bf16 out ----------------
__global__ __launch_bounds__(256) void ln_kernel(
    const float* __restrict__ x, const float* __restrict__ scale,
    const float* __restrict__ shift, unsigned short* __restrict__ out)
{
  const int row = blockIdx.x, tid = threadIdx.x;
  const int lane = tid & 63, wave = tid >> 6;
  const float* xr = x + (size_t)row * DMODEL;
  f32x4 v = *(const f32x4*)&xr[tid * 4];
  float s  = v[0]+v[1]+v[2]+v[3];
  float s2 = v[0]*v[0]+v[1]*v[1]+v[2]*v[2]+v[3]*v[3];
  #pragma unroll
  for (int m = 1; m < 64; m <<= 1) { s += __shfl_xor(s, m); s2 += __shfl_xor(s2, m); }
  __shared__ float red[8];
  if (lane == 0) { red[wave] = s; red[4 + wave] = s2; }
  __syncthreads();
  s  = red[0]+red[1]+red[2]+red[3];
  s2 = red[4]+red[5]+red[6]+red[7];
  float mean = s * (1.0f/DMODEL);
  float var  = s2 * (1.0f/DMODEL) - mean*mean;
  float rstd = rsqrtf(var + 1e-5f);
  us4 o;
  #pragma unroll
  for (int j = 0; j < 4; j++) {
    float val = (v[j]-mean)*rstd*scale[tid*4+j] + shift[tid*4+j];
    o[j] = f2bf(val);
  }
  *(us4*)&out[(size_t)row*DMODEL + tid*4] = o;
}

// ------- weight convert+transpose: W[K][N] fp32 -> Wt[N][K] bf16 -------
__global__ __launch_bounds__(256) void wtrans(
    const float* __restrict__ W, unsigned short* __restrict__ Wt, int K, int N)
{
  __shared__ unsigned short tile[64][72];
  const int tid = threadIdx.x;
  const int nbn = N >> 6;
  const int kt = blockIdx.x / nbn, nt = blockIdx.x % nbn;
  int r = tid >> 2, c0 = (tid & 3) << 4;
  const float* src = W + (size_t)(kt*64 + r)*N + nt*64 + c0;
  #pragma unroll
  for (int j = 0; j < 16; j += 4) {
    f32x4 f = *(const f32x4*)&src[j];
    tile[r][c0+j+0] = f2bf(f[0]); tile[r][c0+j+1] = f2bf(f[1]);
    tile[r][c0+j+2] = f2bf(f[2]); tile[r][c0+j+3] = f2bf(f[3]);
  }
  __syncthreads();
  int n = tid >> 2, k0 = (tid & 3) << 4;
  us8 o0, o1;
  #pragma unroll
  for (int j = 0; j < 8; j++) { o0[j] = tile[k0+j][n]; o1[j] = tile[k0+8+j][n]; }
  unsigned short* dst = Wt + (size_t)(nt*64 + n)*K + kt*64 + k0;
  *(us8*)&dst[0] = o0;
  *(us8*)&dst[8] = o1;
}

// ------- V transpose: v rows [B*S][QKV_LD] (v section) -> vt[(b*H+h)*64+d][S] -------
__global__ __launch_bounds__(256) void vtrans(
    const unsigned short* __restrict__ v, unsigned short* __restrict__ vt)
{
  __shared__ unsigned short tile[64][72];
  const int tid = threadIdx.x;
  const int bh = blockIdx.x >> 5, st = blockIdx.x & 31;
  const int b = bh >> 4, h = bh & 15;
  int r = tid >> 2, c0 = (tid & 3) << 4;
  const unsigned short* src = v + (size_t)(b*S_LEN + st*64 + r)*QKV_LD + h*64 + c0;
  *(us8*)&tile[r][c0]   = *(const us8*)&src[0];
  *(us8*)&tile[r][c0+8] = *(const us8*)&src[8];
  __syncthreads();
  int d = tid >> 2, s0 = (tid & 3) << 4;
  us8 o0, o1;
  #pragma unroll
  for (int j = 0; j < 8; j++) { o0[j] = tile[s0+j][d]; o1[j] = tile[s0+8+j][d]; }
  unsigned short* dst = vt + (size_t)(bh*64 + d)*S_LEN + st*64 + s0;
  *(us8*)&dst[0] = o0;
  *(us8*)&dst[8] = o1;
}

// ---------------- GEMM: C[M,N] = A[M,K] @ Bt[N,K]^T (+bias)(+gelu)(+resid) ----------------
template<bool BIAS, bool RESID, bool GELU_, bool OUTF32>
__global__ __launch_bounds__(256, 2) void gemm_bt(
    const unsigned short* __restrict__ A, const unsigned short* __restrict__ Bt,
    void* Cout, const float* __restrict__ bias, const float* resid,
    int M, int N, int K)
{
  __shared__ unsigned short sA[128*64];
  __shared__ unsigned short sB[128*64];
  const int tid = threadIdx.x;
  const int wave = tid >> 6, lane = tid & 63;
  const int l15 = lane & 15, g = lane >> 4;
  const int nbn = N >> 7;
  const int bm = blockIdx.x / nbn, bn = blockIdx.x % nbn;
  const int wr = (wave >> 1) << 6, wc = (wave & 1) << 6;

  f32x4 acc[4][4] = {};

  const unsigned short* ga0 = A  + (size_t)(bm*128)*K + (lane&7)*8;
  const unsigned short* gb0 = Bt + (size_t)(bn*128)*K + (lane&7)*8;
  const int rrow = (lane >> 3);

  for (int kb = 0; kb < K; kb += 64) {
    #pragma unroll
    for (int i = 0; i < 4; i++) {
      int rr = (wave*4 + i) * 8;
      GLD16(ga0 + (size_t)(rr + rrow)*K + kb, &sA[rr*64]);
      GLD16(gb0 + (size_t)(rr + rrow)*K + kb, &sB[rr*64]);
    }
    __syncthreads();
    #pragma unroll
    for (int kk = 0; kk < 2; kk++) {
      bf16x8 af[4], bfr[4];
      #pragma unroll
      for (int m = 0; m < 4; m++) {
        int base = (wr + m*16 + l15)*64 + kk*32 + g*4;
        af[m] = mk8(*(const us4*)&sA[base], *(const us4*)&sA[base+16]);
      }
      #pragma unroll
      for (int n = 0; n < 4; n++) {
        int base = (wc + n*16 + l15)*64 + kk*32 + g*4;
        bfr[n] = mk8(*(const us4*)&sB[base], *(const us4*)&sB[base+16]);
      }
      #pragma unroll
      for (int m = 0; m < 4; m++)
        #pragma unroll
        for (int n = 0; n < 4; n++)
          acc[m][n] = __builtin_amdgcn_mfma_f32_16x16x32_bf16(af[m], bfr[n], acc[m][n], 0, 0, 0);
    }
    __syncthreads();
  }

  // epilogue: C/D layout col = lane&15, row = 4*(lane>>4)+reg  [verified m89/m91]
  #pragma unroll
  for (int m = 0; m < 4; m++) {
    #pragma unroll
    for (int r = 0; r < 4; r++) {
      int grow = bm*128 + wr + m*16 + g*4 + r;
      #pragma unroll
      for (int n = 0; n < 4; n++) {
        int gcol = bn*128 + wc + n*16 + l15;
        float v = acc[m][n][r];
        if (BIAS) v += bias[gcol];
        if (GELU_) {
          float xx = v;
          v = 0.5f*xx*(1.0f + tanhf(0.7978845608028654f*(xx + 0.044715f*xx*xx*xx)));
        }
        if (RESID) v += resid[(size_t)grow*N + gcol];
        if (OUTF32) ((float*)Cout)[(size_t)grow*N + gcol] = v;
        else ((unsigned short*)Cout)[(size_t)grow*N + gcol] = f2bf(v);
      }
    }
  }
}

// ---------------- causal flash attention ----------------
// grid: (b,h) * (S/64) blocks; 4 waves; wave w owns q rows [q0+16w, +16)
__global__ __launch_bounds__(256) void attn_kernel(
    const unsigned short* __restrict__ qb, const unsigned short* __restrict__ kb,
    const unsigned short* __restrict__ vt, unsigned short* __restrict__ ctx)
{
  __shared__ unsigned short sK[64*64];
  __shared__ unsigned short sV[64*64];
  __shared__ unsigned short sP[4][16*64];
  const int tid = threadIdx.x, wave = tid >> 6, lane = tid & 63;
  const int l15 = lane & 15, g = lane >> 4;
  const int NQT = S_LEN / 64;
  const int qt = blockIdx.x & (NQT - 1);
  const int bh = blockIdx.x / NQT;
  const int b = bh >> 4, h = bh & 15;
  const int q0 = qt * 64;
  const int qrow = q0 + wave * 16;

  // Q fragments (A layout, row = l15, k = d)
  bf16x8 qf[2];
  {
    const unsigned short* qr = qb + (size_t)(b*S_LEN + qrow + l15) * QKV_LD + h*64;
    #pragma unroll
    for (int kk = 0; kk < 2; kk++)
      qf[kk] = mk8(*(const us4*)&qr[kk*32 + g*4], *(const us4*)&qr[kk*32 + g*4 + 16]);
  }

  f32x4 oacc[4] = {};
  float mrow[4], lrow[4];
  #pragma unroll
  for (int r = 0; r < 4; r++) { mrow[r] = -INFINITY; lrow[r] = 0.0f; }

  for (int t = 0; t <= qt; ++t) {
    const int kv0 = t * 64;
    #pragma unroll
    for (int i = 0; i < 2; i++) {
      int rr = (wave*2 + i) * 8;
      int r  = rr + (lane >> 3);
      GLD16(kb + (size_t)(b*S_LEN + kv0 + r)*QKV_LD + h*64 + (lane&7)*8, &sK[rr*64]);
      GLD16(vt + (size_t)(bh*64 + r)*S_LEN + kv0 + (lane&7)*8, &sV[rr*64]);
    }
    __syncthreads();

    // scores = Q K^T
    f32x4 sacc[4] = {};
    #pragma unroll
    for (int kk = 0; kk < 2; kk++) {
      #pragma unroll
      for (int n = 0; n < 4; n++) {
        int base = (n*16 + l15)*64 + kk*32 + g*4;
        bf16x8 kf = mk8(*(const us4*)&sK[base], *(const us4*)&sK[base+16]);
        sacc[n] = __builtin_amdgcn_mfma_f32_16x16x32_bf16(qf[kk], kf, sacc[n], 0, 0, 0);
      }
    }

    // online softmax (per q-row state replicated over 16-lane group)
    float p[4][4], rm[4];
    #pragma unroll
    for (int r = 0; r < 4; r++) rm[r] = -INFINITY;
    #pragma unroll
    for (int n = 0; n < 4; n++) {
      #pragma unroll
      for (int r = 0; r < 4; r++) {
        float sc = sacc[n][r] * 0.125f;  // 1/sqrt(64)
        if (t == qt && (kv0 + n*16 + l15) > (qrow + g*4 + r)) sc = -INFINITY;
        p[n][r] = sc;
        rm[r] = fmaxf(rm[r], sc);
      }
    }
    #pragma unroll
    for (int r = 0; r < 4; r++) {
      float vv = rm[r];
      vv = fmaxf(vv, __shfl_xor(vv, 1));
      vv = fmaxf(vv, __shfl_xor(vv, 2));
      vv = fmaxf(vv, __shfl_xor(vv, 4));
      vv = fmaxf(vv, __shfl_xor(vv, 8));
      float mn = fmaxf(mrow[r], vv);
      float alpha = expf(mrow[r] - mn);   // first tile: exp(-inf)=0
      mrow[r] = mn;
      float sum = 0.0f;
      #pragma unroll
      for (int n = 0; n < 4; n++) {
        float e = expf(p[n][r] - mn);     // masked: exp(-inf)=0
        p[n][r] = e;
        sum += e;
      }
      sum += __shfl_xor(sum, 1);
      sum += __shfl_xor(sum, 2);
      sum += __shfl_xor(sum, 4);
      sum += __shfl_xor(sum, 8);
      lrow[r] = lrow[r]*alpha + sum;
      #pragma unroll
      for (int nd = 0; nd < 4; nd++) oacc[nd][r] *= alpha;
    }

    // P: C/D layout -> LDS -> A layout (per-wave private buffer)
    #pragma unroll
    for (int n = 0; n < 4; n++)
      #pragma unroll
      for (int r = 0; r < 4; r++)
        sP[wave][(g*4 + r)*64 + n*16 + l15] = f2bf(p[n][r]);
    asm volatile("s_waitcnt lgkmcnt(0)" ::: "memory");

    // O += P V   (V staged pre-transposed: sV[d][kv])
    #pragma unroll
    for (int kk = 0; kk < 2; kk++) {
      int pb = l15*64 + kk*32 + g*4;
      bf16x8 pa = mk8(*(const us4*)&sP[wave][pb], *(const us4*)&sP[wave][pb+16]);
      #pragma unroll
      for (int nd = 0; nd < 4; nd++) {
        int base = (nd*16 + l15)*64 + kk*32 + g*4;
        bf16x8 vf = mk8(*(const us4*)&sV[base], *(const us4*)&sV[base+16]);
        oacc[nd] = __builtin_amdgcn_mfma_f32_16x16x32_bf16(pa, vf, oacc[nd], 0, 0, 0);
      }
    }
    __syncthreads();
  }

  #pragma unroll
  for (int r = 0; r < 4; r++) {
    float inv = 1.0f / lrow[r];
    size_t row = (size_t)(b*S_LEN + qrow + g*4 + r);
    #pragma unroll
    for (int nd = 0; nd < 4; nd++)
      ctx[row*DMODEL + h*64 + nd*16 + l15] = f2bf(oacc[nd][r] * inv);
  }
}

// ---------------- host ----------------
extern "C" void kernel_launch(void* const* d_in, const int* in_sizes, int n_in,
                              void* d_out, int out_size, void* d_ws, size_t ws_size,
                              hipStream_t stream)
{
  const float* x    = (const float*)d_in[0];
  const float* Wq   = (const float*)d_in[1];
  const float* Wk   = (const float*)d_in[2];
  const float* Wv   = (const float*)d_in[3];
  const float* Wo   = (const float*)d_in[4];
  const float* bo   = (const float*)d_in[5];
  const float* W1   = (const float*)d_in[6];
  const float* b1   = (const float*)d_in[7];
  const float* W2   = (const float*)d_in[8];
  const float* b2   = (const float*)d_in[9];
  const float* ln1s = (const float*)d_in[10];
  const float* ln1b = (const float*)d_in[11];
  const float* ln2s = (const float*)d_in[12];
  const float* ln2b = (const float*)d_in[13];
  float* out = (float*)d_out;
  (void)in_sizes; (void)n_in; (void)out_size; (void)ws_size;

  char* ws = (char*)d_ws;
  size_t off = 0;
  auto alloc = [&](size_t n) { char* p = ws + off; off += (n + 255) & ~(size_t)255; return p; };
  unsigned short* hbuf  = (unsigned short*)alloc((size_t)NROWS*DMODEL*2);   // LN out (reused for LN2)
  unsigned short* qkv   = (unsigned short*)alloc((size_t)NROWS*QKV_LD*2);   // q|k|v fused
  unsigned short* vtb   = (unsigned short*)alloc((size_t)NROWS*DMODEL*2);   // V^T per (b,h)
  unsigned short* ctx   = (unsigned short*)alloc((size_t)NROWS*DMODEL*2);
  unsigned short* ffn1  = (unsigned short*)alloc((size_t)NROWS*DFF*2);
  unsigned short* wqkvt = (unsigned short*)alloc((size_t)QKV_LD*DMODEL*2);  // Wq^T|Wk^T|Wv^T
  unsigned short* wot   = (unsigned short*)alloc((size_t)DMODEL*DMODEL*2);
  unsigned short* w1t   = (unsigned short*)alloc((size_t)DFF*DMODEL*2);
  unsigned short* w2t   = (unsigned short*)alloc((size_t)DMODEL*DFF*2);

  // weights: fp32 -> bf16 + transpose
  wtrans<<<dim3(16*16), dim3(256), 0, stream>>>(Wq, wqkvt,             DMODEL, DMODEL);
  wtrans<<<dim3(16*16), dim3(256), 0, stream>>>(Wk, wqkvt + 1024*1024, DMODEL, DMODEL);
  wtrans<<<dim3(16*16), dim3(256), 0, stream>>>(Wv, wqkvt + 2048*1024, DMODEL, DMODEL);
  wtrans<<<dim3(16*16), dim3(256), 0, stream>>>(Wo, wot, DMODEL, DMODEL);
  wtrans<<<dim3(16*64), dim3(256), 0, stream>>>(W1, w1t, DMODEL, DFF);
  wtrans<<<dim3(64*16), dim3(256), 0, stream>>>(W2, w2t, DFF, DMODEL);

  // LN1
  ln_kernel<<<dim3(NROWS), dim3(256), 0, stream>>>(x, ln1s, ln1b, hbuf);
  // fused QKV projection: [8192,1024] @ [1024,3072]
  gemm_bt<false,false,false,false><<<dim3(64*24), dim3(256), 0, stream>>>(
      hbuf, wqkvt, (void*)qkv, nullptr, nullptr, NROWS, QKV_LD, DMODEL);
  // V^T
  vtrans<<<dim3(2048), dim3(256), 0, stream>>>(qkv + 2048, vtb);
  // attention
  attn_kernel<<<dim3(2048), dim3(256), 0, stream>>>(qkv, qkv + 1024, vtb, ctx);
  // out proj + bo + residual(x) -> d_out fp32
  gemm_bt<true,true,false,true><<<dim3(64*8), dim3(256), 0, stream>>>(
      ctx, wot, (void*)out, bo, x, NROWS, DMODEL, DMODEL);
  // LN2
  ln_kernel<<<dim3(NROWS), dim3(256), 0, stream>>>(out, ln2s, ln2b, hbuf);
  // FFN1 + b1 + GELU -> bf16
  gemm_bt<true,false,true,false><<<dim3(64*32), dim3(256), 0, stream>>>(
      hbuf, w1t, (void*)ffn1, b1, nullptr, NROWS, DFF, DMODEL);
  // FFN2 + b2 + residual(d_out) -> d_out fp32
  gemm_bt<true,true,false,true><<<dim3(64*8), dim3(256), 0, stream>>>(
      ffn1, w2t, (void*)out, b2, out, NROWS, DMODEL, DFF);
}

// Round 2
// 451.065 us; speedup vs baseline: 5.7939x; 5.7939x over previous
//
#include <hip/hip_runtime.h>
#include <math.h>

// ---- problem constants ----
#define S_LEN  2048
#define DMODEL 1024
#define NHEAD  16
#define BATCH  4
#define NROWS  (BATCH*S_LEN)   // 8192
#define DFF    4096
#define QKV_LD 3072            // fused q|k|v row stride

typedef __attribute__((ext_vector_type(4))) unsigned short us4;
typedef __attribute__((ext_vector_type(8))) unsigned short us8;
typedef __attribute__((ext_vector_type(8))) __bf16 bf16x8;
typedef __attribute__((ext_vector_type(4))) float f32x4;

#if __has_builtin(__builtin_amdgcn_exp2f)
#define EXP2(x) __builtin_amdgcn_exp2f(x)
#else
#define EXP2(x) exp2f(x)
#endif
#if __has_builtin(__builtin_amdgcn_rcpf)
#define RCP(x) __builtin_amdgcn_rcpf(x)
#else
#define RCP(x) (1.0f/(x))
#endif

static __device__ __forceinline__ unsigned short f2bf(float f) {
  unsigned int u = __builtin_bit_cast(unsigned int, f);
  u = (u + 0x7fffu + ((u >> 16) & 1u)) >> 16;
  return (unsigned short)u;
}
#define GLD16(gp, lp) __builtin_amdgcn_global_load_lds( \
    (const __attribute__((address_space(1))) unsigned int*)(gp), \
    (__attribute__((address_space(3))) unsigned int*)(lp), 16, 0, 0)

// ---------------- LayerNorm: fp32 in -> bf16 out ----------------
__global__ __launch_bounds__(256) void ln_kernel(
    const float* __restrict__ x, const float* __restrict__ scale,
    const float* __restrict__ shift, unsigned short* __restrict__ out)
{
  const int row = blockIdx.x, tid = threadIdx.x;
  const int lane = tid & 63, wave = tid >> 6;
  const float* xr = x + (size_t)row * DMODEL;
  f32x4 v = *(const f32x4*)&xr[tid * 4];
  float s  = v[0]+v[1]+v[2]+v[3];
  float s2 = v[0]*v[0]+v[1]*v[1]+v[2]*v[2]+v[3]*v[3];
  #pragma unroll
  for (int m = 1; m < 64; m <<= 1) { s += __shfl_xor(s, m); s2 += __shfl_xor(s2, m); }
  __shared__ float red[8];
  if (lane == 0) { red[wave] = s; red[4 + wave] = s2; }
  __syncthreads();
  s  = red[0]+red[1]+red[2]+red[3];
  s2 = red[4]+red[5]+red[6]+red[7];
  float mean = s * (1.0f/DMODEL);
  float var  = s2 * (1.0f/DMODEL) - mean*mean;
  float rstd = rsqrtf(var + 1e-5f);
  us4 o;
  #pragma unroll
  for (int j = 0; j < 4; j++) {
    float val = (v[j]-mean)*rstd*scale[tid*4+j] + shift[tid*4+j];
    o[j] = f2bf(val);
  }
  *(us4*)&out[(size_t)row*DMODEL + tid*4] = o;
}

// ------- weight convert+transpose: W[K][N] fp32 -> Wt[N][K] bf16 -------
__global__ __launch_bounds__(256) void wtrans(
    const float* __restrict__ W, unsigned short* __restrict__ Wt, int K, int N)
{
  __shared__ unsigned short tile[64][72];
  const int tid = threadIdx.x;
  const int nbn = N >> 6;
  const int kt = blockIdx.x / nbn, nt = blockIdx.x % nbn;
  int r = tid >> 2, c0 = (tid & 3) << 4;
  const float* src = W + (size_t)(kt*64 + r)*N + nt*64 + c0;
  #pragma unroll
  for (int j = 0; j < 16; j += 4) {
    f32x4 f = *(const f32x4*)&src[j];
    tile[r][c0+j+0] = f2bf(f[0]); tile[r][c0+j+1] = f2bf(f[1]);
    tile[r][c0+j+2] = f2bf(f[2]); tile[r][c0+j+3] = f2bf(f[3]);
  }
  __syncthreads();
  int n = tid >> 2, k0 = (tid & 3) << 4;
  us8 o0, o1;
  #pragma unroll
  for (int j = 0; j < 8; j++) { o0[j] = tile[k0+j][n]; o1[j] = tile[k0+8+j][n]; }
  unsigned short* dst = Wt + (size_t)(nt*64 + n)*K + kt*64 + k0;
  *(us8*)&dst[0] = o0;
  *(us8*)&dst[8] = o1;
}

// ------- V transpose: v rows [B*S][QKV_LD] (v section) -> vt[(b*H+h)*64+d][S] -------
__global__ __launch_bounds__(256) void vtrans(
    const unsigned short* __restrict__ v, unsigned short* __restrict__ vt)
{
  __shared__ unsigned short tile[64][72];
  const int tid = threadIdx.x;
  const int bh = blockIdx.x >> 5, st = blockIdx.x & 31;
  const int b = bh >> 4, h = bh & 15;
  int r = tid >> 2, c0 = (tid & 3) << 4;
  const unsigned short* src = v + (size_t)(b*S_LEN + st*64 + r)*QKV_LD + h*64 + c0;
  *(us8*)&tile[r][c0]   = *(const us8*)&src[0];
  *(us8*)&tile[r][c0+8] = *(const us8*)&src[8];
  __syncthreads();
  int d = tid >> 2, s0 = (tid & 3) << 4;
  us8 o0, o1;
  #pragma unroll
  for (int j = 0; j < 8; j++) { o0[j] = tile[s0+j][d]; o1[j] = tile[s0+8+j][d]; }
  unsigned short* dst = vt + (size_t)(bh*64 + d)*S_LEN + st*64 + s0;
  *(us8*)&dst[0] = o0;
  *(us8*)&dst[8] = o1;
}

// ---------------- GEMM: C[M,N] = A[M,K] @ Bt[N,K]^T (+bias)(+gelu)(+resid) ----------------
// LDS tiles [row][64] bf16 with chunk^=(row&7) XOR swizzle (16B chunks).
// global_load_lds writes linearly -> global SOURCE chunk pre-swizzled (rule #21).
template<bool BIAS, bool RESID, bool GELU_, bool OUTF32>
__global__ __launch_bounds__(256, 3) void gemm_bt(
    const unsigned short* __restrict__ A, const unsigned short* __restrict__ Bt,
    void* Cout, const float* __restrict__ bias, const float* resid,
    int M, int N, int K)
{
  __shared__ unsigned short sA[128*64];
  __shared__ unsigned short sB[128*64];
  const int tid = threadIdx.x;
  const int wave = tid >> 6, lane = tid & 63;
  const int l15 = lane & 15, g = lane >> 4, x7 = lane & 7;
  const int nbn = N >> 7;
  const int bm = blockIdx.x / nbn, bn = blockIdx.x % nbn;
  const int wr = (wave >> 1) << 6, wc = (wave & 1) << 6;

  f32x4 acc[4][4] = {};

  const int rrow = lane >> 3;
  const int srcc = (x7 ^ rrow) << 3;           // pre-swizzled source chunk
  const unsigned short* ga0 = A  + (size_t)(bm*128 + rrow)*K + srcc;
  const unsigned short* gb0 = Bt + (size_t)(bn*128 + rrow)*K + srcc;

  for (int kb = 0; kb < K; kb += 64) {
    #pragma unroll
    for (int i = 0; i < 4; i++) {
      int rr = (wave*4 + i) * 8;
      GLD16(ga0 + (size_t)rr*K + kb, &sA[rr*64]);
      GLD16(gb0 + (size_t)rr*K + kb, &sB[rr*64]);
    }
    __syncthreads();
    #pragma unroll
    for (int kk = 0; kk < 2; kk++) {
      const int csw = ((kk*4 + g) ^ x7) << 3;  // swizzled read chunk (row&7 == x7)
      bf16x8 af[4], bfr[4];
      #pragma unroll
      for (int m = 0; m < 4; m++)
        af[m] = *(const bf16x8*)&sA[(wr + m*16 + l15)*64 + csw];
      #pragma unroll
      for (int n = 0; n < 4; n++)
        bfr[n] = *(const bf16x8*)&sB[(wc + n*16 + l15)*64 + csw];
      #pragma unroll
      for (int m = 0; m < 4; m++)
        #pragma unroll
        for (int n = 0; n < 4; n++)
          acc[m][n] = __builtin_amdgcn_mfma_f32_16x16x32_bf16(af[m], bfr[n], acc[m][n], 0, 0, 0);
    }
    __syncthreads();
  }

  // epilogue: C/D layout col = lane&15, row = 4*(lane>>4)+reg
  #pragma unroll
  for (int m = 0; m < 4; m++) {
    #pragma unroll
    for (int r = 0; r < 4; r++) {
      int grow = bm*128 + wr + m*16 + g*4 + r;
      #pragma unroll
      for (int n = 0; n < 4; n++) {
        int gcol = bn*128 + wc + n*16 + l15;
        float v = acc[m][n][r];
        if (BIAS) v += bias[gcol];
        if (GELU_) {
          float xx = v;
          float u = 0.7978845608f*(xx + 0.044715f*xx*xx*xx);
          float e = EXP2(u * 2.88539008f);               // exp(2u)
          float th = 1.0f - 2.0f*RCP(e + 1.0f);          // tanh(u)
          v = 0.5f*xx*(1.0f + th);
        }
        if (RESID) v += resid[(size_t)grow*N + gcol];
        if (OUTF32) ((float*)Cout)[(size_t)grow*N + gcol] = v;
        else ((unsigned short*)Cout)[(size_t)grow*N + gcol] = f2bf(v);
      }
    }
  }
}

// ---------------- causal flash attention ----------------
// heavy-first block order; double-buffered K/V; one barrier per KV tile;
// XOR-swizzled LDS; exp2-domain online softmax.
__global__ __launch_bounds__(256) void attn_kernel(
    const unsigned short* __restrict__ qb, const unsigned short* __restrict__ kb,
    const unsigned short* __restrict__ vt, unsigned short* __restrict__ ctx)
{
  __shared__ unsigned short sK[2][64*64];
  __shared__ unsigned short sV[2][64*64];
  __shared__ unsigned short sP[4][16*64];
  const int tid = threadIdx.x, wave = tid >> 6, lane = tid & 63;
  const int l15 = lane & 15, g = lane >> 4, x7 = lane & 7;
  const int qt = 31 - (blockIdx.x >> 6);      // heavy-first
  const int bh = blockIdx.x & 63;
  const int b = bh >> 4, h = bh & 15;
  const int qrow = qt*64 + wave*16;

  // Q fragments (contiguous-8 k-mapping), from global once
  bf16x8 qf[2];
  {
    const unsigned short* qr = qb + (size_t)(b*S_LEN + qrow + l15) * QKV_LD + h*64;
    qf[0] = *(const bf16x8*)&qr[g*8];
    qf[1] = *(const bf16x8*)&qr[32 + g*8];
  }

  f32x4 oacc[4] = {};
  float mrow[4], lrow[4];
  #pragma unroll
  for (int r = 0; r < 4; r++) { mrow[r] = -INFINITY; lrow[r] = 0.0f; }

  const int rrow = lane >> 3;
  const int srcc = (x7 ^ rrow) << 3;
  const unsigned short* kbase = kb + (size_t)(b*S_LEN)*QKV_LD + h*64 + srcc;
  const unsigned short* vbase = vt + (size_t)(bh*64)*S_LEN + srcc;

#define ASTAGE(buf, t) do { \
    const int kv0_ = (t)*64; \
    _Pragma("unroll") \
    for (int i_ = 0; i_ < 2; i_++) { \
      const int rr_ = (wave*2 + i_)*8; \
      GLD16(kbase + (size_t)(kv0_ + rr_ + rrow)*QKV_LD, &sK[buf][rr_*64]); \
      GLD16(vbase + (size_t)(rr_ + rrow)*S_LEN + kv0_,  &sV[buf][rr_*64]); \
    } } while(0)

  ASTAGE(0, 0);

  const float SCL = 0.18033688f;  // log2(e)/sqrt(64)

  for (int t = 0; t <= qt; ++t) {
    __syncthreads();                       // drains vmcnt: buf[t&1] staged by all
    const int cur = t & 1;
    if (t < qt) ASTAGE(cur ^ 1, t + 1);    // prefetch next tile under compute

    // scores = Q K^T
    f32x4 sacc[4] = {};
    #pragma unroll
    for (int kk = 0; kk < 2; kk++) {
      const int csw = ((kk*4 + g) ^ x7) << 3;
      #pragma unroll
      for (int n = 0; n < 4; n++) {
        bf16x8 kf = *(const bf16x8*)&sK[cur][(n*16 + l15)*64 + csw];
        sacc[n] = __builtin_amdgcn_mfma_f32_16x16x32_bf16(qf[kk], kf, sacc[n], 0, 0, 0);
      }
    }

    // online softmax in log2 domain
    const int kv0 = t*64;
    float p[4][4];
    float rm[4] = {-INFINITY, -INFINITY, -INFINITY, -INFINITY};
    #pragma unroll
    for (int n = 0; n < 4; n++) {
      #pragma unroll
      for (int r = 0; r < 4; r++) {
        float sc = sacc[n][r] * SCL;
        if (t == qt && (kv0 + n*16 + l15) > (qrow + g*4 + r)) sc = -INFINITY;
        p[n][r] = sc;
        rm[r] = fmaxf(rm[r], sc);
      }
    }
    #pragma unroll
    for (int r = 0; r < 4; r++) {
      float vv = rm[r];
      vv = fmaxf(vv, __shfl_xor(vv, 1));
      vv = fmaxf(vv, __shfl_xor(vv, 2));
      vv = fmaxf(vv, __shfl_xor(vv, 4));
      vv = fmaxf(vv, __shfl_xor(vv, 8));
      float mn = fmaxf(mrow[r], vv);
      float alpha = EXP2(mrow[r] - mn);
      mrow[r] = mn;
      float sum = 0.0f;
      #pragma unroll
      for (int n = 0; n < 4; n++) {
        float e = EXP2(p[n][r] - mn);
        p[n][r] = e;
        sum += e;
      }
      sum += __shfl_xor(sum, 1);
      sum += __shfl_xor(sum, 2);
      sum += __shfl_xor(sum, 4);
      sum += __shfl_xor(sum, 8);
      lrow[r] = lrow[r]*alpha + sum;
      #pragma unroll
      for (int nd = 0; nd < 4; nd++) oacc[nd][r] *= alpha;
    }

    // P: C/D layout -> swizzled LDS -> A layout (per-wave private buffer)
    #pragma unroll
    for (int n = 0; n < 4; n++) {
      const int chunk = n*2 + (l15 >> 3);
      #pragma unroll
      for (int r = 0; r < 4; r++) {
        const int prow = g*4 + r;
        sP[wave][prow*64 + ((chunk ^ (prow & 7)) << 3) + x7] = f2bf(p[n][r]);
      }
    }
    asm volatile("s_waitcnt lgkmcnt(0)" ::: "memory");
    __builtin_amdgcn_sched_barrier(0);

    // O += P V   (V staged pre-transposed: sV[d][kv])
    #pragma unroll
    for (int kk = 0; kk < 2; kk++) {
      const int csw = ((kk*4 + g) ^ x7) << 3;
      bf16x8 pa = *(const bf16x8*)&sP[wave][l15*64 + csw];
      #pragma unroll
      for (int nd = 0; nd < 4; nd++) {
        bf16x8 vf = *(const bf16x8*)&sV[cur][(nd*16 + l15)*64 + csw];
        oacc[nd] = __builtin_amdgcn_mfma_f32_16x16x32_bf16(pa, vf, oacc[nd], 0, 0, 0);
      }
    }
  }

  #pragma unroll
  for (int r = 0; r < 4; r++) {
    float inv = 1.0f / lrow[r];
    size_t row = (size_t)(b*S_LEN + qrow + g*4 + r);
    #pragma unroll
    for (int nd = 0; nd < 4; nd++)
      ctx[row*DMODEL + h*64 + nd*16 + l15] = f2bf(oacc[nd][r] * inv);
  }
}

// ---------------- host ----------------
extern "C" void kernel_launch(void* const* d_in, const int* in_sizes, int n_in,
                              void* d_out, int out_size, void* d_ws, size_t ws_size,
                              hipStream_t stream)
{
  const float* x    = (const float*)d_in[0];
  const float* Wq   = (const float*)d_in[1];
  const float* Wk   = (const float*)d_in[2];
  const float* Wv   = (const float*)d_in[3];
  const float* Wo   = (const float*)d_in[4];
  const float* bo   = (const float*)d_in[5];
  const float* W1   = (const float*)d_in[6];
  const float* b1   = (const float*)d_in[7];
  const float* W2   = (const float*)d_in[8];
  const float* b2   = (const float*)d_in[9];
  const float* ln1s = (const float*)d_in[10];
  const float* ln1b = (const float*)d_in[11];
  const float* ln2s = (const float*)d_in[12];
  const float* ln2b = (const float*)d_in[13];
  float* out = (float*)d_out;
  (void)in_sizes; (void)n_in; (void)out_size; (void)ws_size;

  char* ws = (char*)d_ws;
  size_t off = 0;
  auto alloc = [&](size_t n) { char* p = ws + off; off += (n + 255) & ~(size_t)255; return p; };
  unsigned short* hbuf  = (unsigned short*)alloc((size_t)NROWS*DMODEL*2);   // LN out (reused for LN2)
  unsigned short* qkv   = (unsigned short*)alloc((size_t)NROWS*QKV_LD*2);   // q|k|v fused
  unsigned short* vtb   = (unsigned short*)alloc((size_t)NROWS*DMODEL*2);   // V^T per (b,h)
  unsigned short* ctx   = (unsigned short*)alloc((size_t)NROWS*DMODEL*2);
  unsigned short* ffn1  = (unsigned short*)alloc((size_t)NROWS*DFF*2);
  unsigned short* wqkvt = (unsigned short*)alloc((size_t)QKV_LD*DMODEL*2);  // Wq^T|Wk^T|Wv^T
  unsigned short* wot   = (unsigned short*)alloc((size_t)DMODEL*DMODEL*2);
  unsigned short* w1t   = (unsigned short*)alloc((size_t)DFF*DMODEL*2);
  unsigned short* w2t   = (unsigned short*)alloc((size_t)DMODEL*DFF*2);

  // weights: fp32 -> bf16 + transpose
  wtrans<<<dim3(16*16), dim3(256), 0, stream>>>(Wq, wqkvt,             DMODEL, DMODEL);
  wtrans<<<dim3(16*16), dim3(256), 0, stream>>>(Wk, wqkvt + 1024*1024, DMODEL, DMODEL);
  wtrans<<<dim3(16*16), dim3(256), 0, stream>>>(Wv, wqkvt + 2048*1024, DMODEL, DMODEL);
  wtrans<<<dim3(16*16), dim3(256), 0, stream>>>(Wo, wot, DMODEL, DMODEL);
  wtrans<<<dim3(16*64), dim3(256), 0, stream>>>(W1, w1t, DMODEL, DFF);
  wtrans<<<dim3(64*16), dim3(256), 0, stream>>>(W2, w2t, DFF, DMODEL);

  // LN1
  ln_kernel<<<dim3(NROWS), dim3(256), 0, stream>>>(x, ln1s, ln1b, hbuf);
  // fused QKV projection: [8192,1024] @ [1024,3072]
  gemm_bt<false,false,false,false><<<dim3(64*24), dim3(256), 0, stream>>>(
      hbuf, wqkvt, (void*)qkv, nullptr, nullptr, NROWS, QKV_LD, DMODEL);
  // V^T
  vtrans<<<dim3(2048), dim3(256), 0, stream>>>(qkv + 2048, vtb);
  // attention
  attn_kernel<<<dim3(2048), dim3(256), 0, stream>>>(qkv, qkv + 1024, vtb, ctx);
  // out proj + bo + residual(x) -> d_out fp32
  gemm_bt<true,true,false,true><<<dim3(64*8), dim3(256), 0, stream>>>(
      ctx, wot, (void*)out, bo, x, NROWS, DMODEL, DMODEL);
  // LN2
  ln_kernel<<<dim3(NROWS), dim3(256), 0, stream>>>(out, ln2s, ln2b, hbuf);
  // FFN1 + b1 + GELU -> bf16
  gemm_bt<true,false,true,false><<<dim3(64*32), dim3(256), 0, stream>>>(
      hbuf, w1t, (void*)ffn1, b1, nullptr, NROWS, DFF, DMODEL);
  // FFN2 + b2 + residual(d_out) -> d_out fp32
  gemm_bt<true,true,false,true><<<dim3(64*8), dim3(256), 0, stream>>>(
      ffn1, w2t, (void*)out, b2, out, NROWS, DMODEL, DFF);
}

// Round 3
// 436.862 us; speedup vs baseline: 5.9822x; 1.0325x over previous
//
#include <hip/hip_runtime.h>
#include <math.h>

// ---- problem constants ----
#define S_LEN  2048
#define DMODEL 1024
#define NHEAD  16
#define BATCH  4
#define NROWS  (BATCH*S_LEN)   // 8192
#define DFF    4096
#define QKV_LD 3072            // fused q|k|v row stride

typedef __attribute__((ext_vector_type(4))) unsigned short us4;
typedef __attribute__((ext_vector_type(8))) unsigned short us8;
typedef __attribute__((ext_vector_type(8))) __bf16 bf16x8;
typedef __attribute__((ext_vector_type(4))) float f32x4;

#if __has_builtin(__builtin_amdgcn_exp2f)
#define EXP2(x) __builtin_amdgcn_exp2f(x)
#else
#define EXP2(x) exp2f(x)
#endif
#if __has_builtin(__builtin_amdgcn_rcpf)
#define RCP(x) __builtin_amdgcn_rcpf(x)
#else
#define RCP(x) (1.0f/(x))
#endif

static __device__ __forceinline__ unsigned short f2bf(float f) {
  unsigned int u = __builtin_bit_cast(unsigned int, f);
  u = (u + 0x7fffu + ((u >> 16) & 1u)) >> 16;
  return (unsigned short)u;
}
#define GLD16(gp, lp) __builtin_amdgcn_global_load_lds( \
    (const __attribute__((address_space(1))) unsigned int*)(gp), \
    (__attribute__((address_space(3))) unsigned int*)(lp), 16, 0, 0)

// ---------------- LayerNorm: fp32 in -> bf16 out ----------------
__global__ __launch_bounds__(256) void ln_kernel(
    const float* __restrict__ x, const float* __restrict__ scale,
    const float* __restrict__ shift, unsigned short* __restrict__ out)
{
  const int row = blockIdx.x, tid = threadIdx.x;
  const int lane = tid & 63, wave = tid >> 6;
  const float* xr = x + (size_t)row * DMODEL;
  f32x4 v = *(const f32x4*)&xr[tid * 4];
  float s  = v[0]+v[1]+v[2]+v[3];
  float s2 = v[0]*v[0]+v[1]*v[1]+v[2]*v[2]+v[3]*v[3];
  #pragma unroll
  for (int m = 1; m < 64; m <<= 1) { s += __shfl_xor(s, m); s2 += __shfl_xor(s2, m); }
  __shared__ float red[8];
  if (lane == 0) { red[wave] = s; red[4 + wave] = s2; }
  __syncthreads();
  s  = red[0]+red[1]+red[2]+red[3];
  s2 = red[4]+red[5]+red[6]+red[7];
  float mean = s * (1.0f/DMODEL);
  float var  = s2 * (1.0f/DMODEL) - mean*mean;
  float rstd = rsqrtf(var + 1e-5f);
  us4 o;
  #pragma unroll
  for (int j = 0; j < 4; j++) {
    float val = (v[j]-mean)*rstd*scale[tid*4+j] + shift[tid*4+j];
    o[j] = f2bf(val);
  }
  *(us4*)&out[(size_t)row*DMODEL + tid*4] = o;
}

// ------- weight convert+transpose: W[K][N] fp32 -> Wt[N][K] bf16 (× scl) -------
__global__ __launch_bounds__(256) void wtrans(
    const float* __restrict__ W, unsigned short* __restrict__ Wt, int K, int N,
    float scl)
{
  __shared__ unsigned short tile[64][72];
  const int tid = threadIdx.x;
  const int nbn = N >> 6;
  const int kt = blockIdx.x / nbn, nt = blockIdx.x % nbn;
  int r = tid >> 2, c0 = (tid & 3) << 4;
  const float* src = W + (size_t)(kt*64 + r)*N + nt*64 + c0;
  #pragma unroll
  for (int j = 0; j < 16; j += 4) {
    f32x4 f = *(const f32x4*)&src[j];
    tile[r][c0+j+0] = f2bf(f[0]*scl); tile[r][c0+j+1] = f2bf(f[1]*scl);
    tile[r][c0+j+2] = f2bf(f[2]*scl); tile[r][c0+j+3] = f2bf(f[3]*scl);
  }
  __syncthreads();
  int n = tid >> 2, k0 = (tid & 3) << 4;
  us8 o0, o1;
  #pragma unroll
  for (int j = 0; j < 8; j++) { o0[j] = tile[k0+j][n]; o1[j] = tile[k0+8+j][n]; }
  unsigned short* dst = Wt + (size_t)(nt*64 + n)*K + kt*64 + k0;
  *(us8*)&dst[0] = o0;
  *(us8*)&dst[8] = o1;
}

// ------- V transpose: v rows [B*S][QKV_LD] (v section) -> vt[(b*H+h)*64+d][S] -------
__global__ __launch_bounds__(256) void vtrans(
    const unsigned short* __restrict__ v, unsigned short* __restrict__ vt)
{
  __shared__ unsigned short tile[64][72];
  const int tid = threadIdx.x;
  const int bh = blockIdx.x >> 5, st = blockIdx.x & 31;
  const int b = bh >> 4, h = bh & 15;
  int r = tid >> 2, c0 = (tid & 3) << 4;
  const unsigned short* src = v + (size_t)(b*S_LEN + st*64 + r)*QKV_LD + h*64 + c0;
  *(us8*)&tile[r][c0]   = *(const us8*)&src[0];
  *(us8*)&tile[r][c0+8] = *(const us8*)&src[8];
  __syncthreads();
  int d = tid >> 2, s0 = (tid & 3) << 4;
  us8 o0, o1;
  #pragma unroll
  for (int j = 0; j < 8; j++) { o0[j] = tile[s0+j][d]; o1[j] = tile[s0+8+j][d]; }
  unsigned short* dst = vt + (size_t)(bh*64 + d)*S_LEN + st*64 + s0;
  *(us8*)&dst[0] = o0;
  *(us8*)&dst[8] = o1;
}

// ---------------- 128x128 GEMM (Wo / FFN2): proven m97-class ----------------
template<bool BIAS, bool RESID, bool GELU_, bool OUTF32>
__global__ __launch_bounds__(256, 3) void gemm_bt(
    const unsigned short* __restrict__ A, const unsigned short* __restrict__ Bt,
    void* Cout, const float* __restrict__ bias, const float* resid,
    int M, int N, int K)
{
  __shared__ unsigned short sA[128*64];
  __shared__ unsigned short sB[128*64];
  const int tid = threadIdx.x;
  const int wave = tid >> 6, lane = tid & 63;
  const int l15 = lane & 15, g = lane >> 4, x7 = lane & 7;
  const int nbn = N >> 7;
  const int bm = blockIdx.x / nbn, bn = blockIdx.x % nbn;
  const int wr = (wave >> 1) << 6, wc = (wave & 1) << 6;

  f32x4 acc[4][4] = {};

  const int rrow = lane >> 3;
  const int srcc = (x7 ^ rrow) << 3;           // pre-swizzled source chunk
  const unsigned short* ga0 = A  + (size_t)(bm*128 + rrow)*K + srcc;
  const unsigned short* gb0 = Bt + (size_t)(bn*128 + rrow)*K + srcc;

  for (int kb = 0; kb < K; kb += 64) {
    #pragma unroll
    for (int i = 0; i < 4; i++) {
      int rr = (wave*4 + i) * 8;
      GLD16(ga0 + (size_t)rr*K + kb, &sA[rr*64]);
      GLD16(gb0 + (size_t)rr*K + kb, &sB[rr*64]);
    }
    __syncthreads();
    #pragma unroll
    for (int kk = 0; kk < 2; kk++) {
      const int csw = ((kk*4 + g) ^ x7) << 3;
      bf16x8 af[4], bfr[4];
      #pragma unroll
      for (int m = 0; m < 4; m++)
        af[m] = *(const bf16x8*)&sA[(wr + m*16 + l15)*64 + csw];
      #pragma unroll
      for (int n = 0; n < 4; n++)
        bfr[n] = *(const bf16x8*)&sB[(wc + n*16 + l15)*64 + csw];
      #pragma unroll
      for (int m = 0; m < 4; m++)
        #pragma unroll
        for (int n = 0; n < 4; n++)
          acc[m][n] = __builtin_amdgcn_mfma_f32_16x16x32_bf16(af[m], bfr[n], acc[m][n], 0, 0, 0);
    }
    __syncthreads();
  }

  #pragma unroll
  for (int m = 0; m < 4; m++) {
    #pragma unroll
    for (int r = 0; r < 4; r++) {
      int grow = bm*128 + wr + m*16 + g*4 + r;
      #pragma unroll
      for (int n = 0; n < 4; n++) {
        int gcol = bn*128 + wc + n*16 + l15;
        float v = acc[m][n][r];
        if (BIAS) v += bias[gcol];
        if (GELU_) {
          float xx = v;
          float u = 0.7978845608f*(xx + 0.044715f*xx*xx*xx);
          float e = EXP2(u * 2.88539008f);
          float th = 1.0f - 2.0f*RCP(e + 1.0f);
          v = 0.5f*xx*(1.0f + th);
        }
        if (RESID) v += resid[(size_t)grow*N + gcol];
        if (OUTF32) ((float*)Cout)[(size_t)grow*N + gcol] = v;
        else ((unsigned short*)Cout)[(size_t)grow*N + gcol] = f2bf(v);
      }
    }
  }
}

// ---------------- 256x256 8-phase GEMM (QKV / FFN1), bf16 out ----------------
// 8 waves (2M x 4N), per-wave C = 128x64 = acc[8][4]. BK=64, LDS 128 KB.
// Per K-tile: 4 phases x 16 MFMA. B-frags reg-cached at phase L1 (frees B LDS).
// Staging slots: L1/L2 -> A(t+1) into opposite buf (freed at t-1 L4-end);
//                L3/L4 -> B(t+2) into current buf's B (freed at this L1-end).
// One counted vmcnt(4) per K-tile at L1 (A(t)+B(t) landed, B(t+1) in flight).
template<bool BIAS, bool GELU_>
__global__ __launch_bounds__(512, 2) void gemm256(
    const unsigned short* __restrict__ A, const unsigned short* __restrict__ Bt,
    unsigned short* __restrict__ Cout, const float* __restrict__ bias,
    int M, int N, int K)
{
  __shared__ unsigned short sA[2][256*64];
  __shared__ unsigned short sB[2][256*64];
  const int tid = threadIdx.x;
  const int wave = tid >> 6, lane = tid & 63;
  const int wm = wave >> 2, wn = wave & 3;
  const int l15 = lane & 15, g = lane >> 4, x7 = lane & 7, r8 = lane >> 3;
  const int srcc = (x7 ^ r8) << 3;
  const int nbn = N >> 8;
  const int bm = blockIdx.x / nbn, bn = blockIdx.x % nbn;
  const unsigned short* gA = A  + (size_t)(bm*256)*K;
  const unsigned short* gB = Bt + (size_t)(bn*256)*K;
  const int NT = K >> 6;

  f32x4 acc[8][4] = {};

#define STAGE6(sarr, gp, h, kb) do { \
    _Pragma("unroll") \
    for (int j_ = 0; j_ < 2; j_++) { \
      GLD16((gp) + (size_t)((h)*128 + j_*64 + wave*8 + r8)*K + (kb) + srcc, \
            &(sarr)[((h)*128 + j_*64 + wave*8)*64]); \
    } } while (0)

#define RDA(m, kk) (*(const bf16x8*)&cA[(wm*128 + (m)*16 + l15)*64 + ((((kk)*4+g)^x7)<<3)])
#define RDB(n, kk) (*(const bf16x8*)&cB[(wn*64  + (n)*16 + l15)*64 + ((((kk)*4+g)^x7)<<3)])

#define PH_MFMA(p) do { \
    __builtin_amdgcn_s_setprio(1); \
    _Pragma("unroll") for (int mm_ = 0; mm_ < 2; mm_++) \
    _Pragma("unroll") for (int n_ = 0; n_ < 4; n_++) \
    _Pragma("unroll") for (int kk_ = 0; kk_ < 2; kk_++) \
      acc[(p)*2+mm_][n_] = __builtin_amdgcn_mfma_f32_16x16x32_bf16( \
          af[mm_][kk_], bfr[n_][kk_], acc[(p)*2+mm_][n_], 0, 0, 0); \
    __builtin_amdgcn_s_setprio(0); \
  } while (0)

  // prologue: tile0 (B,A) -> buf0 ; B(tile1) -> buf1   [12 loads/thread]
  STAGE6(sB[0], gB, 0, 0); STAGE6(sB[0], gB, 1, 0);
  STAGE6(sA[0], gA, 0, 0); STAGE6(sA[0], gA, 1, 0);
  if (NT > 1) { STAGE6(sB[1], gB, 0, 64); STAGE6(sB[1], gB, 1, 64); }

  for (int t = 0; t < NT; ++t) {
    const int c = t & 1;
    const unsigned short* cA = sA[c];
    const unsigned short* cB = sB[c];
    unsigned short* nA = sA[c ^ 1];
    unsigned short* curB = sB[c];
    const int kb1 = (t + 1) * 64, kb2 = (t + 2) * 64;

    bf16x8 bfr[4][2], af[2][2];

    // ---- L1 ----
    if (t < NT - 1) { asm volatile("s_waitcnt vmcnt(4)" ::: "memory"); }
    else            { asm volatile("s_waitcnt vmcnt(0)" ::: "memory"); }
    __builtin_amdgcn_s_barrier();
    __builtin_amdgcn_sched_barrier(0);
    #pragma unroll
    for (int n = 0; n < 4; n++) { bfr[n][0] = RDB(n, 0); bfr[n][1] = RDB(n, 1); }
    af[0][0] = RDA(0, 0); af[0][1] = RDA(0, 1);
    af[1][0] = RDA(1, 0); af[1][1] = RDA(1, 1);
    if (t + 1 < NT) STAGE6(nA, gA, 0, kb1);
    PH_MFMA(0);
    __builtin_amdgcn_s_barrier();

    // ---- L2 ----
    af[0][0] = RDA(2, 0); af[0][1] = RDA(2, 1);
    af[1][0] = RDA(3, 0); af[1][1] = RDA(3, 1);
    if (t + 1 < NT) STAGE6(nA, gA, 1, kb1);
    PH_MFMA(1);
    __builtin_amdgcn_s_barrier();

    // ---- L3 ----
    af[0][0] = RDA(4, 0); af[0][1] = RDA(4, 1);
    af[1][0] = RDA(5, 0); af[1][1] = RDA(5, 1);
    if (t + 2 < NT) STAGE6(curB, gB, 0, kb2);
    PH_MFMA(2);
    __builtin_amdgcn_s_barrier();

    // ---- L4 ----
    af[0][0] = RDA(6, 0); af[0][1] = RDA(6, 1);
    af[1][0] = RDA(7, 0); af[1][1] = RDA(7, 1);
    if (t + 2 < NT) STAGE6(curB, gB, 1, kb2);
    PH_MFMA(3);
    __builtin_amdgcn_s_barrier();
  }

  // epilogue: row = bm*256 + wm*128 + m*16 + g*4 + r ; col = bn*256 + wn*64 + n*16 + l15
  #pragma unroll
  for (int m = 0; m < 8; m++) {
    #pragma unroll
    for (int r = 0; r < 4; r++) {
      int grow = bm*256 + wm*128 + m*16 + g*4 + r;
      #pragma unroll
      for (int n = 0; n < 4; n++) {
        int gcol = bn*256 + wn*64 + n*16 + l15;
        float v = acc[m][n][r];
        if (BIAS) v += bias[gcol];
        if (GELU_) {
          float xx = v;
          float u = 0.7978845608f*(xx + 0.044715f*xx*xx*xx);
          float e = EXP2(u * 2.88539008f);
          float th = 1.0f - 2.0f*RCP(e + 1.0f);
          v = 0.5f*xx*(1.0f + th);
        }
        Cout[(size_t)grow*N + gcol] = f2bf(v);
      }
    }
  }
#undef STAGE6
#undef RDA
#undef RDB
#undef PH_MFMA
}

// ---------------- causal flash attention ----------------
// Wq pre-scaled by log2(e)/sqrt(64) -> scores arrive in exp2 domain.
__global__ __launch_bounds__(256) void attn_kernel(
    const unsigned short* __restrict__ qb, const unsigned short* __restrict__ kb,
    const unsigned short* __restrict__ vt, unsigned short* __restrict__ ctx)
{
  __shared__ unsigned short sK[2][64*64];
  __shared__ unsigned short sV[2][64*64];
  __shared__ unsigned short sP[4][16*64];
  const int tid = threadIdx.x, wave = tid >> 6, lane = tid & 63;
  const int l15 = lane & 15, g = lane >> 4, x7 = lane & 7;
  const int qt = 31 - (blockIdx.x >> 6);      // heavy-first
  const int bh = blockIdx.x & 63;
  const int b = bh >> 4, h = bh & 15;
  const int qrow = qt*64 + wave*16;

  bf16x8 qf[2];
  {
    const unsigned short* qr = qb + (size_t)(b*S_LEN + qrow + l15) * QKV_LD + h*64;
    qf[0] = *(const bf16x8*)&qr[g*8];
    qf[1] = *(const bf16x8*)&qr[32 + g*8];
  }

  f32x4 oacc[4] = {};
  float mrow[4], lrow[4];
  #pragma unroll
  for (int r = 0; r < 4; r++) { mrow[r] = -INFINITY; lrow[r] = 0.0f; }

  const int rrow = lane >> 3;
  const int srcc = (x7 ^ rrow) << 3;
  const unsigned short* kbase = kb + (size_t)(b*S_LEN)*QKV_LD + h*64 + srcc;
  const unsigned short* vbase = vt + (size_t)(bh*64)*S_LEN + srcc;

#define ASTAGE(buf, t) do { \
    const int kv0_ = (t)*64; \
    _Pragma("unroll") \
    for (int i_ = 0; i_ < 2; i_++) { \
      const int rr_ = (wave*2 + i_)*8; \
      GLD16(kbase + (size_t)(kv0_ + rr_ + rrow)*QKV_LD, &sK[buf][rr_*64]); \
      GLD16(vbase + (size_t)(rr_ + rrow)*S_LEN + kv0_,  &sV[buf][rr_*64]); \
    } } while(0)

  ASTAGE(0, 0);

  for (int t = 0; t <= qt; ++t) {
    __syncthreads();
    const int cur = t & 1;
    if (t < qt) ASTAGE(cur ^ 1, t + 1);

    f32x4 sacc[4] = {};
    #pragma unroll
    for (int kk = 0; kk < 2; kk++) {
      const int csw = ((kk*4 + g) ^ x7) << 3;
      #pragma unroll
      for (int n = 0; n < 4; n++) {
        bf16x8 kf = *(const bf16x8*)&sK[cur][(n*16 + l15)*64 + csw];
        sacc[n] = __builtin_amdgcn_mfma_f32_16x16x32_bf16(qf[kk], kf, sacc[n], 0, 0, 0);
      }
    }

    const int kv0 = t*64;
    float p[4][4];
    float rm[4] = {-INFINITY, -INFINITY, -INFINITY, -INFINITY};
    #pragma unroll
    for (int n = 0; n < 4; n++) {
      #pragma unroll
      for (int r = 0; r < 4; r++) {
        float sc = sacc[n][r];     // already log2-scaled via Wq
        if (t == qt && (kv0 + n*16 + l15) > (qrow + g*4 + r)) sc = -INFINITY;
        p[n][r] = sc;
        rm[r] = fmaxf(rm[r], sc);
      }
    }
    #pragma unroll
    for (int r = 0; r < 4; r++) {
      float vv = rm[r];
      vv = fmaxf(vv, __shfl_xor(vv, 1));
      vv = fmaxf(vv, __shfl_xor(vv, 2));
      vv = fmaxf(vv, __shfl_xor(vv, 4));
      vv = fmaxf(vv, __shfl_xor(vv, 8));
      float mn = fmaxf(mrow[r], vv);
      float alpha = EXP2(mrow[r] - mn);
      mrow[r] = mn;
      float sum = 0.0f;
      #pragma unroll
      for (int n = 0; n < 4; n++) {
        float e = EXP2(p[n][r] - mn);
        p[n][r] = e;
        sum += e;
      }
      sum += __shfl_xor(sum, 1);
      sum += __shfl_xor(sum, 2);
      sum += __shfl_xor(sum, 4);
      sum += __shfl_xor(sum, 8);
      lrow[r] = lrow[r]*alpha + sum;
      #pragma unroll
      for (int nd = 0; nd < 4; nd++) oacc[nd][r] *= alpha;
    }

    #pragma unroll
    for (int n = 0; n < 4; n++) {
      const int chunk = n*2 + (l15 >> 3);
      #pragma unroll
      for (int r = 0; r < 4; r++) {
        const int prow = g*4 + r;
        sP[wave][prow*64 + ((chunk ^ (prow & 7)) << 3) + x7] = f2bf(p[n][r]);
      }
    }
    asm volatile("s_waitcnt lgkmcnt(0)" ::: "memory");
    __builtin_amdgcn_sched_barrier(0);

    #pragma unroll
    for (int kk = 0; kk < 2; kk++) {
      const int csw = ((kk*4 + g) ^ x7) << 3;
      bf16x8 pa = *(const bf16x8*)&sP[wave][l15*64 + csw];
      #pragma unroll
      for (int nd = 0; nd < 4; nd++) {
        bf16x8 vf = *(const bf16x8*)&sV[cur][(nd*16 + l15)*64 + csw];
        oacc[nd] = __builtin_amdgcn_mfma_f32_16x16x32_bf16(pa, vf, oacc[nd], 0, 0, 0);
      }
    }
  }

  #pragma unroll
  for (int r = 0; r < 4; r++) {
    float inv = 1.0f / lrow[r];
    size_t row = (size_t)(b*S_LEN + qrow + g*4 + r);
    #pragma unroll
    for (int nd = 0; nd < 4; nd++)
      ctx[row*DMODEL + h*64 + nd*16 + l15] = f2bf(oacc[nd][r] * inv);
  }
}

// ---------------- host ----------------
extern "C" void kernel_launch(void* const* d_in, const int* in_sizes, int n_in,
                              void* d_out, int out_size, void* d_ws, size_t ws_size,
                              hipStream_t stream)
{
  const float* x    = (const float*)d_in[0];
  const float* Wq   = (const float*)d_in[1];
  const float* Wk   = (const float*)d_in[2];
  const float* Wv   = (const float*)d_in[3];
  const float* Wo   = (const float*)d_in[4];
  const float* bo   = (const float*)d_in[5];
  const float* W1   = (const float*)d_in[6];
  const float* b1   = (const float*)d_in[7];
  const float* W2   = (const float*)d_in[8];
  const float* b2   = (const float*)d_in[9];
  const float* ln1s = (const float*)d_in[10];
  const float* ln1b = (const float*)d_in[11];
  const float* ln2s = (const float*)d_in[12];
  const float* ln2b = (const float*)d_in[13];
  float* out = (float*)d_out;
  (void)in_sizes; (void)n_in; (void)out_size; (void)ws_size;

  char* ws = (char*)d_ws;
  size_t off = 0;
  auto alloc = [&](size_t n) { char* p = ws + off; off += (n + 255) & ~(size_t)255; return p; };
  unsigned short* hbuf  = (unsigned short*)alloc((size_t)NROWS*DMODEL*2);
  unsigned short* qkv   = (unsigned short*)alloc((size_t)NROWS*QKV_LD*2);
  unsigned short* vtb   = (unsigned short*)alloc((size_t)NROWS*DMODEL*2);
  unsigned short* ctx   = (unsigned short*)alloc((size_t)NROWS*DMODEL*2);
  unsigned short* ffn1  = (unsigned short*)alloc((size_t)NROWS*DFF*2);
  unsigned short* wqkvt = (unsigned short*)alloc((size_t)QKV_LD*DMODEL*2);
  unsigned short* wot   = (unsigned short*)alloc((size_t)DMODEL*DMODEL*2);
  unsigned short* w1t   = (unsigned short*)alloc((size_t)DFF*DMODEL*2);
  unsigned short* w2t   = (unsigned short*)alloc((size_t)DMODEL*DFF*2);

  const float SCLQ = 0.18033688011f;  // log2(e)/sqrt(64)

  wtrans<<<dim3(16*16), dim3(256), 0, stream>>>(Wq, wqkvt,             DMODEL, DMODEL, SCLQ);
  wtrans<<<dim3(16*16), dim3(256), 0, stream>>>(Wk, wqkvt + 1024*1024, DMODEL, DMODEL, 1.0f);
  wtrans<<<dim3(16*16), dim3(256), 0, stream>>>(Wv, wqkvt + 2048*1024, DMODEL, DMODEL, 1.0f);
  wtrans<<<dim3(16*16), dim3(256), 0, stream>>>(Wo, wot, DMODEL, DMODEL, 1.0f);
  wtrans<<<dim3(16*64), dim3(256), 0, stream>>>(W1, w1t, DMODEL, DFF, 1.0f);
  wtrans<<<dim3(64*16), dim3(256), 0, stream>>>(W2, w2t, DFF, DMODEL, 1.0f);

  // LN1
  ln_kernel<<<dim3(NROWS), dim3(256), 0, stream>>>(x, ln1s, ln1b, hbuf);
  // fused QKV projection: [8192,1024] @ [1024,3072]  (256x256 8-phase)
  gemm256<false,false><<<dim3(32*12), dim3(512), 0, stream>>>(
      hbuf, wqkvt, qkv, nullptr, NROWS, QKV_LD, DMODEL);
  // V^T
  vtrans<<<dim3(2048), dim3(256), 0, stream>>>(qkv + 2048, vtb);
  // attention
  attn_kernel<<<dim3(2048), dim3(256), 0, stream>>>(qkv, qkv + 1024, vtb, ctx);
  // out proj + bo + residual(x) -> d_out fp32
  gemm_bt<true,true,false,true><<<dim3(64*8), dim3(256), 0, stream>>>(
      ctx, wot, (void*)out, bo, x, NROWS, DMODEL, DMODEL);
  // LN2
  ln_kernel<<<dim3(NROWS), dim3(256), 0, stream>>>(out, ln2s, ln2b, hbuf);
  // FFN1 + b1 + GELU -> bf16  (256x256 8-phase)
  gemm256<true,true><<<dim3(32*16), dim3(512), 0, stream>>>(
      hbuf, w1t, ffn1, b1, NROWS, DFF, DMODEL);
  // FFN2 + b2 + residual(d_out) -> d_out fp32
  gemm_bt<true,true,false,true><<<dim3(64*8), dim3(256), 0, stream>>>(
      ffn1, w2t, (void*)out, b2, out, NROWS, DMODEL, DFF);
}

// Round 4
// 434.512 us; speedup vs baseline: 6.0146x; 1.0054x over previous
//
#include <hip/hip_runtime.h>
#include <math.h>

// ---- problem constants ----
#define S_LEN  2048
#define DMODEL 1024
#define NHEAD  16
#define BATCH  4
#define NROWS  (BATCH*S_LEN)   // 8192
#define DFF    4096
#define QKV_LD 3072            // fused q|k|v row stride

typedef __attribute__((ext_vector_type(4))) unsigned short us4;
typedef __attribute__((ext_vector_type(8))) unsigned short us8;
typedef __attribute__((ext_vector_type(8))) __bf16 bf16x8;
typedef __attribute__((ext_vector_type(4))) float f32x4;

#if __has_builtin(__builtin_amdgcn_exp2f)
#define EXP2(x) __builtin_amdgcn_exp2f(x)
#else
#define EXP2(x) exp2f(x)
#endif
#if __has_builtin(__builtin_amdgcn_rcpf)
#define RCP(x) __builtin_amdgcn_rcpf(x)
#else
#define RCP(x) (1.0f/(x))
#endif

static __device__ __forceinline__ unsigned short f2bf(float f) {
  __bf16 b = (__bf16)f;                       // HW RNE convert on gfx950
  return __builtin_bit_cast(unsigned short, b);
}
#define GLD16(gp, lp) __builtin_amdgcn_global_load_lds( \
    (const __attribute__((address_space(1))) unsigned int*)(gp), \
    (__attribute__((address_space(3))) unsigned int*)(lp), 16, 0, 0)

// ---------------- LayerNorm: fp32 in -> bf16 out ----------------
__global__ __launch_bounds__(256) void ln_kernel(
    const float* __restrict__ x, const float* __restrict__ scale,
    const float* __restrict__ shift, unsigned short* __restrict__ out)
{
  const int row = blockIdx.x, tid = threadIdx.x;
  const int lane = tid & 63, wave = tid >> 6;
  const float* xr = x + (size_t)row * DMODEL;
  f32x4 v = *(const f32x4*)&xr[tid * 4];
  float s  = v[0]+v[1]+v[2]+v[3];
  float s2 = v[0]*v[0]+v[1]*v[1]+v[2]*v[2]+v[3]*v[3];
  #pragma unroll
  for (int m = 1; m < 64; m <<= 1) { s += __shfl_xor(s, m); s2 += __shfl_xor(s2, m); }
  __shared__ float red[8];
  if (lane == 0) { red[wave] = s; red[4 + wave] = s2; }
  __syncthreads();
  s  = red[0]+red[1]+red[2]+red[3];
  s2 = red[4]+red[5]+red[6]+red[7];
  float mean = s * (1.0f/DMODEL);
  float var  = s2 * (1.0f/DMODEL) - mean*mean;
  float rstd = rsqrtf(var + 1e-5f);
  us4 o;
  #pragma unroll
  for (int j = 0; j < 4; j++) {
    float val = (v[j]-mean)*rstd*scale[tid*4+j] + shift[tid*4+j];
    o[j] = f2bf(val);
  }
  *(us4*)&out[(size_t)row*DMODEL + tid*4] = o;
}

// ------- merged weight convert+transpose: all 6 weights in one launch -------
// W[K][N] fp32 -> Wt[N][K] bf16 (x scl).  3072 blocks total.
__global__ __launch_bounds__(256) void wtrans_all(
    const float* __restrict__ Wq, const float* __restrict__ Wk,
    const float* __restrict__ Wv, const float* __restrict__ Wo,
    const float* __restrict__ W1, const float* __restrict__ W2,
    unsigned short* __restrict__ wqkvt, unsigned short* __restrict__ wot,
    unsigned short* __restrict__ w1t, unsigned short* __restrict__ w2t,
    float sclq)
{
  __shared__ unsigned short tile[64][72];
  const int bid = blockIdx.x, tid = threadIdx.x;
  const float* W; unsigned short* Wt; int K, N, sub; float scl = 1.0f;
  if (bid < 1024) {
    int wsel = bid >> 8; sub = bid & 255; K = 1024; N = 1024;
    W  = (wsel == 0) ? Wq : (wsel == 1) ? Wk : (wsel == 2) ? Wv : Wo;
    Wt = (wsel == 0) ? wqkvt : (wsel == 1) ? wqkvt + 1024*1024
       : (wsel == 2) ? wqkvt + 2048*1024 : wot;
    if (wsel == 0) scl = sclq;
  } else if (bid < 2048) { sub = bid - 1024; K = 1024; N = 4096; W = W1; Wt = w1t; }
  else                   { sub = bid - 2048; K = 4096; N = 1024; W = W2; Wt = w2t; }
  const int nbn = N >> 6;
  const int kt = sub / nbn, nt = sub % nbn;
  int r = tid >> 2, c0 = (tid & 3) << 4;
  const float* src = W + (size_t)(kt*64 + r)*N + nt*64 + c0;
  #pragma unroll
  for (int j = 0; j < 16; j += 4) {
    f32x4 f = *(const f32x4*)&src[j];
    tile[r][c0+j+0] = f2bf(f[0]*scl); tile[r][c0+j+1] = f2bf(f[1]*scl);
    tile[r][c0+j+2] = f2bf(f[2]*scl); tile[r][c0+j+3] = f2bf(f[3]*scl);
  }
  __syncthreads();
  int n = tid >> 2, k0 = (tid & 3) << 4;
  us8 o0, o1;
  #pragma unroll
  for (int j = 0; j < 8; j++) { o0[j] = tile[k0+j][n]; o1[j] = tile[k0+8+j][n]; }
  unsigned short* dst = Wt + (size_t)(nt*64 + n)*K + kt*64 + k0;
  *(us8*)&dst[0] = o0;
  *(us8*)&dst[8] = o1;
}

// ------- V transpose: v rows [B*S][QKV_LD] (v section) -> vt[(b*H+h)*64+d][S] -------
__global__ __launch_bounds__(256) void vtrans(
    const unsigned short* __restrict__ v, unsigned short* __restrict__ vt)
{
  __shared__ unsigned short tile[64][72];
  const int tid = threadIdx.x;
  const int bh = blockIdx.x >> 5, st = blockIdx.x & 31;
  const int b = bh >> 4, h = bh & 15;
  int r = tid >> 2, c0 = (tid & 3) << 4;
  const unsigned short* src = v + (size_t)(b*S_LEN + st*64 + r)*QKV_LD + h*64 + c0;
  *(us8*)&tile[r][c0]   = *(const us8*)&src[0];
  *(us8*)&tile[r][c0+8] = *(const us8*)&src[8];
  __syncthreads();
  int d = tid >> 2, s0 = (tid & 3) << 4;
  us8 o0, o1;
  #pragma unroll
  for (int j = 0; j < 8; j++) { o0[j] = tile[s0+j][d]; o1[j] = tile[s0+8+j][d]; }
  unsigned short* dst = vt + (size_t)(bh*64 + d)*S_LEN + st*64 + s0;
  *(us8*)&dst[0] = o0;
  *(us8*)&dst[8] = o1;
}

// ------- 256xBN pipelined GEMM: C = A[M,K] @ Bt[N,K]^T (+bias)(+gelu)(+resid) -------
// 8 waves (2M x 4N), per-wave 128 x BN/4. BK=64, XOR-swizzled LDS, GLD16 staging.
// Barrier-minimal: per K-tile {vmcnt(BQ); barrier; [ph1: B-regcache + A m0-1 + stageA(t+1,h0) + 16 MFMA]
//  [ph2: A m2-3 + stageA(t+1,h1) + MFMA] barrier [ph3: A m4-5 + stageB(t+2,h0) + MFMA]
//  [ph4: A m6-7 + stageB(t+2,h1) + MFMA]}.  B(t+2) into current buf is safe: B reg-cached at ph1,
//  gated by the mid barrier. A(t+1) into other buf: consumed last iter, gated by ph1 barrier.
template<int BN, bool BIAS, bool GELU_, bool RESID, bool OUTF32>
__global__ __launch_bounds__(512, 2) void gemm256(
    const unsigned short* __restrict__ A, const unsigned short* __restrict__ Bt,
    void* Cout, const float* __restrict__ bias, const float* resid,
    int M, int N, int K)
{
  constexpr int WN = BN / 4;       // per-wave N span
  constexpr int NF = WN / 16;      // B frags per wave
  __shared__ unsigned short sA[2][256*64];
  __shared__ unsigned short sB[2][BN*64];
  const int tid = threadIdx.x;
  const int wave = tid >> 6, lane = tid & 63;
  const int wm = wave >> 2, wn = wave & 3;
  const int l15 = lane & 15, g = lane >> 4, x7 = lane & 7, r8 = lane >> 3;
  const int srcc = (x7 ^ r8) << 3;
  const int nbn = N / BN;
  const int bm = blockIdx.x / nbn, bn = blockIdx.x % nbn;
  const unsigned short* gA = A  + (size_t)(bm*256)*K;
  const unsigned short* gB = Bt + (size_t)(bn*BN)*K;
  const int NT = K >> 6;

  f32x4 acc[8][NF] = {};

#define STAGEA(buf, h, kb) do { \
    _Pragma("unroll") \
    for (int j_ = 0; j_ < 2; j_++) \
      GLD16(gA + (size_t)((h)*128 + j_*64 + wave*8 + r8)*K + (kb) + srcc, \
            &sA[buf][((h)*128 + j_*64 + wave*8)*64]); \
  } while (0)
#define STAGEB(buf, h, kb) do { \
    if (BN == 256) { \
      _Pragma("unroll") \
      for (int j_ = 0; j_ < 2; j_++) \
        GLD16(gB + (size_t)((h)*128 + j_*64 + wave*8 + r8)*K + (kb) + srcc, \
              &sB[buf][((h)*128 + j_*64 + wave*8)*64]); \
    } else { \
      GLD16(gB + (size_t)((h)*64 + wave*8 + r8)*K + (kb) + srcc, \
            &sB[buf][((h)*64 + wave*8)*64]); \
    } \
  } while (0)
#define RDA_(m, kk) (*(const bf16x8*)&cA[(wm*128 + (m)*16 + l15)*64 + ((((kk)*4+g)^x7)<<3)])
#define RDB_(n, kk) (*(const bf16x8*)&cB[(wn*WN + (n)*16 + l15)*64 + ((((kk)*4+g)^x7)<<3)])
#define PH(p) do { \
    __builtin_amdgcn_s_setprio(1); \
    _Pragma("unroll") for (int mm_ = 0; mm_ < 2; mm_++) \
    _Pragma("unroll") for (int n_ = 0; n_ < NF; n_++) \
    _Pragma("unroll") for (int kk_ = 0; kk_ < 2; kk_++) \
      acc[(p)*2+mm_][n_] = __builtin_amdgcn_mfma_f32_16x16x32_bf16( \
          af[mm_][kk_], bfr[n_][kk_], acc[(p)*2+mm_][n_], 0, 0, 0); \
    __builtin_amdgcn_s_setprio(0); \
  } while (0)

  // prologue: B(0),A(0) -> buf0 ; B(1) -> buf1
  STAGEB(0, 0, 0); STAGEB(0, 1, 0);
  STAGEA(0, 0, 0); STAGEA(0, 1, 0);
  STAGEB(1, 0, 64); STAGEB(1, 1, 64);

  for (int t = 0; t < NT; ++t) {
    const int c = t & 1;
    const unsigned short* cA = sA[c];
    const unsigned short* cB = sB[c];
    const int kb1 = (t + 1) * 64, kb2 = (t + 2) * 64;
    bf16x8 af[2][2], bfr[NF][2];

    if (t < NT - 1) {
      if constexpr (BN == 256) asm volatile("s_waitcnt vmcnt(4)" ::: "memory");
      else                     asm volatile("s_waitcnt vmcnt(2)" ::: "memory");
    } else {
      asm volatile("s_waitcnt vmcnt(0)" ::: "memory");
    }
    __builtin_amdgcn_s_barrier();
    __builtin_amdgcn_sched_barrier(0);

    // ---- ph1: B reg-cache + A m0,m1 ----
    #pragma unroll
    for (int n = 0; n < NF; n++) { bfr[n][0] = RDB_(n, 0); bfr[n][1] = RDB_(n, 1); }
    af[0][0] = RDA_(0, 0); af[0][1] = RDA_(0, 1);
    af[1][0] = RDA_(1, 0); af[1][1] = RDA_(1, 1);
    if (t + 1 < NT) STAGEA(c ^ 1, 0, kb1);
    PH(0);
    // ---- ph2 ----
    af[0][0] = RDA_(2, 0); af[0][1] = RDA_(2, 1);
    af[1][0] = RDA_(3, 0); af[1][1] = RDA_(3, 1);
    if (t + 1 < NT) STAGEA(c ^ 1, 1, kb1);
    PH(1);
    __builtin_amdgcn_s_barrier();        // B-region recycle gate
    // ---- ph3 ----
    af[0][0] = RDA_(4, 0); af[0][1] = RDA_(4, 1);
    af[1][0] = RDA_(5, 0); af[1][1] = RDA_(5, 1);
    if (t + 2 < NT) STAGEB(c, 0, kb2);
    PH(2);
    // ---- ph4 ----
    af[0][0] = RDA_(6, 0); af[0][1] = RDA_(6, 1);
    af[1][0] = RDA_(7, 0); af[1][1] = RDA_(7, 1);
    if (t + 2 < NT) STAGEB(c, 1, kb2);
    PH(3);
  }

  // epilogue: row = bm*256 + wm*128 + m*16 + g*4 + r ; col = bn*BN + wn*WN + n*16 + l15
  #pragma unroll
  for (int m = 0; m < 8; m++) {
    #pragma unroll
    for (int r = 0; r < 4; r++) {
      int grow = bm*256 + wm*128 + m*16 + g*4 + r;
      #pragma unroll
      for (int n = 0; n < NF; n++) {
        int gcol = bn*BN + wn*WN + n*16 + l15;
        float v = acc[m][n][r];
        if (BIAS) v += bias[gcol];
        if (GELU_) {
          float xx = v;
          float u = 0.7978845608f*(xx + 0.044715f*xx*xx*xx);
          float e = EXP2(u * 2.88539008f);
          float th = 1.0f - 2.0f*RCP(e + 1.0f);
          v = 0.5f*xx*(1.0f + th);
        }
        if (RESID) v += resid[(size_t)grow*N + gcol];
        if (OUTF32) ((float*)Cout)[(size_t)grow*N + gcol] = v;
        else ((unsigned short*)Cout)[(size_t)grow*N + gcol] = f2bf(v);
      }
    }
  }
#undef STAGEA
#undef STAGEB
#undef RDA_
#undef RDB_
#undef PH
}

// ---------------- causal flash attention ----------------
// Wq pre-scaled by log2(e)/sqrt(64) -> scores in exp2 domain. Defer-max (T13).
__global__ __launch_bounds__(256) void attn_kernel(
    const unsigned short* __restrict__ qb, const unsigned short* __restrict__ kb,
    const unsigned short* __restrict__ vt, unsigned short* __restrict__ ctx)
{
  __shared__ unsigned short sK[2][64*64];
  __shared__ unsigned short sV[2][64*64];
  __shared__ unsigned short sP[4][16*64];
  const int tid = threadIdx.x, wave = tid >> 6, lane = tid & 63;
  const int l15 = lane & 15, g = lane >> 4, x7 = lane & 7;
  const int qt = 31 - (blockIdx.x >> 6);      // heavy-first
  const int bh = blockIdx.x & 63;
  const int b = bh >> 4, h = bh & 15;
  const int qrow = qt*64 + wave*16;

  bf16x8 qf[2];
  {
    const unsigned short* qr = qb + (size_t)(b*S_LEN + qrow + l15) * QKV_LD + h*64;
    qf[0] = *(const bf16x8*)&qr[g*8];
    qf[1] = *(const bf16x8*)&qr[32 + g*8];
  }

  f32x4 oacc[4] = {};
  float mrow[4], lrow[4];
  #pragma unroll
  for (int r = 0; r < 4; r++) { mrow[r] = -INFINITY; lrow[r] = 0.0f; }

  const int rrow = lane >> 3;
  const int srcc = (x7 ^ rrow) << 3;
  const unsigned short* kbase = kb + (size_t)(b*S_LEN)*QKV_LD + h*64 + srcc;
  const unsigned short* vbase = vt + (size_t)(bh*64)*S_LEN + srcc;

#define ASTAGE(buf, t) do { \
    const int kv0_ = (t)*64; \
    _Pragma("unroll") \
    for (int i_ = 0; i_ < 2; i_++) { \
      const int rr_ = (wave*2 + i_)*8; \
      GLD16(kbase + (size_t)(kv0_ + rr_ + rrow)*QKV_LD, &sK[buf][rr_*64]); \
      GLD16(vbase + (size_t)(rr_ + rrow)*S_LEN + kv0_,  &sV[buf][rr_*64]); \
    } } while(0)

  ASTAGE(0, 0);

  for (int t = 0; t <= qt; ++t) {
    __syncthreads();
    const int cur = t & 1;
    if (t < qt) ASTAGE(cur ^ 1, t + 1);

    f32x4 sacc[4] = {};
    __builtin_amdgcn_s_setprio(1);
    #pragma unroll
    for (int kk = 0; kk < 2; kk++) {
      const int csw = ((kk*4 + g) ^ x7) << 3;
      #pragma unroll
      for (int n = 0; n < 4; n++) {
        bf16x8 kf = *(const bf16x8*)&sK[cur][(n*16 + l15)*64 + csw];
        sacc[n] = __builtin_amdgcn_mfma_f32_16x16x32_bf16(qf[kk], kf, sacc[n], 0, 0, 0);
      }
    }
    __builtin_amdgcn_s_setprio(0);

    const int kv0 = t*64;
    float p[4][4], gm[4];
    #pragma unroll
    for (int r = 0; r < 4; r++) {
      float rm = -INFINITY;
      #pragma unroll
      for (int n = 0; n < 4; n++) {
        float sc = sacc[n][r];     // already log2-scaled via Wq
        if (t == qt && (kv0 + n*16 + l15) > (qrow + g*4 + r)) sc = -INFINITY;
        p[n][r] = sc;
        rm = fmaxf(rm, sc);
      }
      rm = fmaxf(rm, __shfl_xor(rm, 1));
      rm = fmaxf(rm, __shfl_xor(rm, 2));
      rm = fmaxf(rm, __shfl_xor(rm, 4));
      rm = fmaxf(rm, __shfl_xor(rm, 8));
      gm[r] = rm;
    }
    // defer-max: rescale only when some row max grew past threshold (wave-uniform)
    bool need = (gm[0] > mrow[0] + 8.0f) | (gm[1] > mrow[1] + 8.0f) |
                (gm[2] > mrow[2] + 8.0f) | (gm[3] > mrow[3] + 8.0f);
    if (__any(need)) {
      #pragma unroll
      for (int r = 0; r < 4; r++) {
        float mn = fmaxf(mrow[r], gm[r]);
        float alpha = EXP2(mrow[r] - mn);
        mrow[r] = mn;
        lrow[r] *= alpha;
        #pragma unroll
        for (int nd = 0; nd < 4; nd++) oacc[nd][r] *= alpha;
      }
    }
    #pragma unroll
    for (int r = 0; r < 4; r++) {
      float sum = 0.0f;
      #pragma unroll
      for (int n = 0; n < 4; n++) {
        float e = EXP2(p[n][r] - mrow[r]);
        p[n][r] = e;
        sum += e;
      }
      sum += __shfl_xor(sum, 1);
      sum += __shfl_xor(sum, 2);
      sum += __shfl_xor(sum, 4);
      sum += __shfl_xor(sum, 8);
      lrow[r] += sum;
    }

    #pragma unroll
    for (int n = 0; n < 4; n++) {
      const int chunk = n*2 + (l15 >> 3);
      #pragma unroll
      for (int r = 0; r < 4; r++) {
        const int prow = g*4 + r;
        sP[wave][prow*64 + ((chunk ^ (prow & 7)) << 3) + x7] = f2bf(p[n][r]);
      }
    }
    asm volatile("s_waitcnt lgkmcnt(0)" ::: "memory");
    __builtin_amdgcn_sched_barrier(0);

    __builtin_amdgcn_s_setprio(1);
    #pragma unroll
    for (int kk = 0; kk < 2; kk++) {
      const int csw = ((kk*4 + g) ^ x7) << 3;
      bf16x8 pa = *(const bf16x8*)&sP[wave][l15*64 + csw];
      #pragma unroll
      for (int nd = 0; nd < 4; nd++) {
        bf16x8 vf = *(const bf16x8*)&sV[cur][(nd*16 + l15)*64 + csw];
        oacc[nd] = __builtin_amdgcn_mfma_f32_16x16x32_bf16(pa, vf, oacc[nd], 0, 0, 0);
      }
    }
    __builtin_amdgcn_s_setprio(0);
  }

  #pragma unroll
  for (int r = 0; r < 4; r++) {
    float inv = 1.0f / lrow[r];
    size_t row = (size_t)(b*S_LEN + qrow + g*4 + r);
    #pragma unroll
    for (int nd = 0; nd < 4; nd++)
      ctx[row*DMODEL + h*64 + nd*16 + l15] = f2bf(oacc[nd][r] * inv);
  }
}

// ---------------- host ----------------
extern "C" void kernel_launch(void* const* d_in, const int* in_sizes, int n_in,
                              void* d_out, int out_size, void* d_ws, size_t ws_size,
                              hipStream_t stream)
{
  const float* x    = (const float*)d_in[0];
  const float* Wq   = (const float*)d_in[1];
  const float* Wk   = (const float*)d_in[2];
  const float* Wv   = (const float*)d_in[3];
  const float* Wo   = (const float*)d_in[4];
  const float* bo   = (const float*)d_in[5];
  const float* W1   = (const float*)d_in[6];
  const float* b1   = (const float*)d_in[7];
  const float* W2   = (const float*)d_in[8];
  const float* b2   = (const float*)d_in[9];
  const float* ln1s = (const float*)d_in[10];
  const float* ln1b = (const float*)d_in[11];
  const float* ln2s = (const float*)d_in[12];
  const float* ln2b = (const float*)d_in[13];
  float* out = (float*)d_out;
  (void)in_sizes; (void)n_in; (void)out_size; (void)ws_size;

  char* ws = (char*)d_ws;
  size_t off = 0;
  auto alloc = [&](size_t n) { char* p = ws + off; off += (n + 255) & ~(size_t)255; return p; };
  unsigned short* hbuf  = (unsigned short*)alloc((size_t)NROWS*DMODEL*2);
  unsigned short* qkv   = (unsigned short*)alloc((size_t)NROWS*QKV_LD*2);
  unsigned short* vtb   = (unsigned short*)alloc((size_t)NROWS*DMODEL*2);
  unsigned short* ctx   = (unsigned short*)alloc((size_t)NROWS*DMODEL*2);
  unsigned short* ffn1  = (unsigned short*)alloc((size_t)NROWS*DFF*2);
  unsigned short* wqkvt = (unsigned short*)alloc((size_t)QKV_LD*DMODEL*2);
  unsigned short* wot   = (unsigned short*)alloc((size_t)DMODEL*DMODEL*2);
  unsigned short* w1t   = (unsigned short*)alloc((size_t)DFF*DMODEL*2);
  unsigned short* w2t   = (unsigned short*)alloc((size_t)DMODEL*DFF*2);

  const float SCLQ = 0.18033688011f;  // log2(e)/sqrt(64)

  // all weight transposes in one launch
  wtrans_all<<<dim3(3072), dim3(256), 0, stream>>>(
      Wq, Wk, Wv, Wo, W1, W2, wqkvt, wot, w1t, w2t, SCLQ);

  // LN1
  ln_kernel<<<dim3(NROWS), dim3(256), 0, stream>>>(x, ln1s, ln1b, hbuf);
  // fused QKV projection: [8192,1024] @ [1024,3072]
  gemm256<256,false,false,false,false><<<dim3(32*12), dim3(512), 0, stream>>>(
      hbuf, wqkvt, (void*)qkv, nullptr, nullptr, NROWS, QKV_LD, DMODEL);
  // V^T
  vtrans<<<dim3(2048), dim3(256), 0, stream>>>(qkv + 2048, vtb);
  // attention
  attn_kernel<<<dim3(2048), dim3(256), 0, stream>>>(qkv, qkv + 1024, vtb, ctx);
  // out proj + bo + residual(x) -> d_out fp32   (256x128 tiles, 256 blocks)
  gemm256<128,true,false,true,true><<<dim3(32*8), dim3(512), 0, stream>>>(
      ctx, wot, (void*)out, bo, x, NROWS, DMODEL, DMODEL);
  // LN2
  ln_kernel<<<dim3(NROWS), dim3(256), 0, stream>>>(out, ln2s, ln2b, hbuf);
  // FFN1 + b1 + GELU -> bf16
  gemm256<256,true,true,false,false><<<dim3(32*16), dim3(512), 0, stream>>>(
      hbuf, w1t, (void*)ffn1, b1, nullptr, NROWS, DFF, DMODEL);
  // FFN2 + b2 + residual(d_out) -> d_out fp32   (256x128 tiles, 256 blocks)
  gemm256<128,true,false,true,true><<<dim3(32*8), dim3(512), 0, stream>>>(
      ffn1, w2t, (void*)out, b2, out, NROWS, DMODEL, DFF);
}

// Round 5
// 432.697 us; speedup vs baseline: 6.0398x; 1.0042x over previous
//
#include <hip/hip_runtime.h>
#include <math.h>

// ---- problem constants ----
#define S_LEN  2048
#define DMODEL 1024
#define NHEAD  16
#define BATCH  4
#define NROWS  (BATCH*S_LEN)   // 8192
#define DFF    4096
#define QKV_LD 3072            // fused q|k|v row stride

typedef __attribute__((ext_vector_type(4))) unsigned short us4;
typedef __attribute__((ext_vector_type(8))) unsigned short us8;
typedef __attribute__((ext_vector_type(8))) __bf16 bf16x8;
typedef __attribute__((ext_vector_type(4))) float f32x4;

#if __has_builtin(__builtin_amdgcn_exp2f)
#define EXP2(x) __builtin_amdgcn_exp2f(x)
#else
#define EXP2(x) exp2f(x)
#endif
#if __has_builtin(__builtin_amdgcn_rcpf)
#define RCP(x) __builtin_amdgcn_rcpf(x)
#else
#define RCP(x) (1.0f/(x))
#endif

static __device__ __forceinline__ unsigned short f2bf(float f) {
  __bf16 b = (__bf16)f;                       // HW RNE convert on gfx950
  return __builtin_bit_cast(unsigned short, b);
}
#define GLD16(gp, lp) __builtin_amdgcn_global_load_lds( \
    (const __attribute__((address_space(1))) unsigned int*)(gp), \
    (__attribute__((address_space(3))) unsigned int*)(lp), 16, 0, 0)

// ---------------- LayerNorm: fp32 in -> bf16 out ----------------
__global__ __launch_bounds__(256) void ln_kernel(
    const float* __restrict__ x, const float* __restrict__ scale,
    const float* __restrict__ shift, unsigned short* __restrict__ out)
{
  const int row = blockIdx.x, tid = threadIdx.x;
  const int lane = tid & 63, wave = tid >> 6;
  const float* xr = x + (size_t)row * DMODEL;
  f32x4 v = *(const f32x4*)&xr[tid * 4];
  float s  = v[0]+v[1]+v[2]+v[3];
  float s2 = v[0]*v[0]+v[1]*v[1]+v[2]*v[2]+v[3]*v[3];
  #pragma unroll
  for (int m = 1; m < 64; m <<= 1) { s += __shfl_xor(s, m); s2 += __shfl_xor(s2, m); }
  __shared__ float red[8];
  if (lane == 0) { red[wave] = s; red[4 + wave] = s2; }
  __syncthreads();
  s  = red[0]+red[1]+red[2]+red[3];
  s2 = red[4]+red[5]+red[6]+red[7];
  float mean = s * (1.0f/DMODEL);
  float var  = s2 * (1.0f/DMODEL) - mean*mean;
  float rstd = rsqrtf(var + 1e-5f);
  us4 o;
  #pragma unroll
  for (int j = 0; j < 4; j++) {
    float val = (v[j]-mean)*rstd*scale[tid*4+j] + shift[tid*4+j];
    o[j] = f2bf(val);
  }
  *(us4*)&out[(size_t)row*DMODEL + tid*4] = o;
}

// ------- merged weight convert+transpose: all 6 weights in one launch -------
__global__ __launch_bounds__(256) void wtrans_all(
    const float* __restrict__ Wq, const float* __restrict__ Wk,
    const float* __restrict__ Wv, const float* __restrict__ Wo,
    const float* __restrict__ W1, const float* __restrict__ W2,
    unsigned short* __restrict__ wqkvt, unsigned short* __restrict__ wot,
    unsigned short* __restrict__ w1t, unsigned short* __restrict__ w2t,
    float sclq)
{
  __shared__ unsigned short tile[64][72];
  const int bid = blockIdx.x, tid = threadIdx.x;
  const float* W; unsigned short* Wt; int K, N, sub; float scl = 1.0f;
  if (bid < 1024) {
    int wsel = bid >> 8; sub = bid & 255; K = 1024; N = 1024;
    W  = (wsel == 0) ? Wq : (wsel == 1) ? Wk : (wsel == 2) ? Wv : Wo;
    Wt = (wsel == 0) ? wqkvt : (wsel == 1) ? wqkvt + 1024*1024
       : (wsel == 2) ? wqkvt + 2048*1024 : wot;
    if (wsel == 0) scl = sclq;
  } else if (bid < 2048) { sub = bid - 1024; K = 1024; N = 4096; W = W1; Wt = w1t; }
  else                   { sub = bid - 2048; K = 4096; N = 1024; W = W2; Wt = w2t; }
  const int nbn = N >> 6;
  const int kt = sub / nbn, nt = sub % nbn;
  int r = tid >> 2, c0 = (tid & 3) << 4;
  const float* src = W + (size_t)(kt*64 + r)*N + nt*64 + c0;
  #pragma unroll
  for (int j = 0; j < 16; j += 4) {
    f32x4 f = *(const f32x4*)&src[j];
    tile[r][c0+j+0] = f2bf(f[0]*scl); tile[r][c0+j+1] = f2bf(f[1]*scl);
    tile[r][c0+j+2] = f2bf(f[2]*scl); tile[r][c0+j+3] = f2bf(f[3]*scl);
  }
  __syncthreads();
  int n = tid >> 2, k0 = (tid & 3) << 4;
  us8 o0, o1;
  #pragma unroll
  for (int j = 0; j < 8; j++) { o0[j] = tile[k0+j][n]; o1[j] = tile[k0+8+j][n]; }
  unsigned short* dst = Wt + (size_t)(nt*64 + n)*K + kt*64 + k0;
  *(us8*)&dst[0] = o0;
  *(us8*)&dst[8] = o1;
}

// ------- V transpose: v rows [B*S][QKV_LD] (v section) -> vt[(b*H+h)*64+d][S] -------
__global__ __launch_bounds__(256) void vtrans(
    const unsigned short* __restrict__ v, unsigned short* __restrict__ vt)
{
  __shared__ unsigned short tile[64][72];
  const int tid = threadIdx.x;
  const int bh = blockIdx.x >> 5, st = blockIdx.x & 31;
  const int b = bh >> 4, h = bh & 15;
  int r = tid >> 2, c0 = (tid & 3) << 4;
  const unsigned short* src = v + (size_t)(b*S_LEN + st*64 + r)*QKV_LD + h*64 + c0;
  *(us8*)&tile[r][c0]   = *(const us8*)&src[0];
  *(us8*)&tile[r][c0+8] = *(const us8*)&src[8];
  __syncthreads();
  int d = tid >> 2, s0 = (tid & 3) << 4;
  us8 o0, o1;
  #pragma unroll
  for (int j = 0; j < 8; j++) { o0[j] = tile[s0+j][d]; o1[j] = tile[s0+8+j][d]; }
  unsigned short* dst = vt + (size_t)(bh*64 + d)*S_LEN + st*64 + s0;
  *(us8*)&dst[0] = o0;
  *(us8*)&dst[8] = o1;
}

// ------- 256xBN pipelined GEMM: C = A[M,K] @ Bt[N,K]^T (+bias)(+gelu)(+resid) -------
template<int BN, bool BIAS, bool GELU_, bool RESID, bool OUTF32>
__global__ __launch_bounds__(512, 2) void gemm256(
    const unsigned short* __restrict__ A, const unsigned short* __restrict__ Bt,
    void* Cout, const float* __restrict__ bias, const float* resid,
    int M, int N, int K)
{
  constexpr int WN = BN / 4;       // per-wave N span
  constexpr int NF = WN / 16;      // B frags per wave
  __shared__ unsigned short sA[2][256*64];
  __shared__ unsigned short sB[2][BN*64];
  const int tid = threadIdx.x;
  const int wave = tid >> 6, lane = tid & 63;
  const int wm = wave >> 2, wn = wave & 3;
  const int l15 = lane & 15, g = lane >> 4, x7 = lane & 7, r8 = lane >> 3;
  const int srcc = (x7 ^ r8) << 3;
  const int nbn = N / BN;
  const int bm = blockIdx.x / nbn, bn = blockIdx.x % nbn;
  const unsigned short* gA = A  + (size_t)(bm*256)*K;
  const unsigned short* gB = Bt + (size_t)(bn*BN)*K;
  const int NT = K >> 6;

  f32x4 acc[8][NF] = {};

#define STAGEA(buf, h, kb) do { \
    _Pragma("unroll") \
    for (int j_ = 0; j_ < 2; j_++) \
      GLD16(gA + (size_t)((h)*128 + j_*64 + wave*8 + r8)*K + (kb) + srcc, \
            &sA[buf][((h)*128 + j_*64 + wave*8)*64]); \
  } while (0)
#define STAGEB(buf, h, kb) do { \
    if (BN == 256) { \
      _Pragma("unroll") \
      for (int j_ = 0; j_ < 2; j_++) \
        GLD16(gB + (size_t)((h)*128 + j_*64 + wave*8 + r8)*K + (kb) + srcc, \
              &sB[buf][((h)*128 + j_*64 + wave*8)*64]); \
    } else { \
      GLD16(gB + (size_t)((h)*64 + wave*8 + r8)*K + (kb) + srcc, \
            &sB[buf][((h)*64 + wave*8)*64]); \
    } \
  } while (0)
#define RDA_(m, kk) (*(const bf16x8*)&cA[(wm*128 + (m)*16 + l15)*64 + ((((kk)*4+g)^x7)<<3)])
#define RDB_(n, kk) (*(const bf16x8*)&cB[(wn*WN + (n)*16 + l15)*64 + ((((kk)*4+g)^x7)<<3)])
#define PH(p) do { \
    __builtin_amdgcn_s_setprio(1); \
    _Pragma("unroll") for (int mm_ = 0; mm_ < 2; mm_++) \
    _Pragma("unroll") for (int n_ = 0; n_ < NF; n_++) \
    _Pragma("unroll") for (int kk_ = 0; kk_ < 2; kk_++) \
      acc[(p)*2+mm_][n_] = __builtin_amdgcn_mfma_f32_16x16x32_bf16( \
          af[mm_][kk_], bfr[n_][kk_], acc[(p)*2+mm_][n_], 0, 0, 0); \
    __builtin_amdgcn_s_setprio(0); \
  } while (0)

  // prologue: B(0),A(0) -> buf0 ; B(1) -> buf1
  STAGEB(0, 0, 0); STAGEB(0, 1, 0);
  STAGEA(0, 0, 0); STAGEA(0, 1, 0);
  STAGEB(1, 0, 64); STAGEB(1, 1, 64);

  for (int t = 0; t < NT; ++t) {
    const int c = t & 1;
    const unsigned short* cA = sA[c];
    const unsigned short* cB = sB[c];
    const int kb1 = (t + 1) * 64, kb2 = (t + 2) * 64;
    bf16x8 af[2][2], bfr[NF][2];

    if (t < NT - 1) {
      if constexpr (BN == 256) asm volatile("s_waitcnt vmcnt(4)" ::: "memory");
      else                     asm volatile("s_waitcnt vmcnt(2)" ::: "memory");
    } else {
      asm volatile("s_waitcnt vmcnt(0)" ::: "memory");
    }
    __builtin_amdgcn_s_barrier();
    __builtin_amdgcn_sched_barrier(0);

    // ---- ph1: B reg-cache + A m0,m1 ----
    #pragma unroll
    for (int n = 0; n < NF; n++) { bfr[n][0] = RDB_(n, 0); bfr[n][1] = RDB_(n, 1); }
    af[0][0] = RDA_(0, 0); af[0][1] = RDA_(0, 1);
    af[1][0] = RDA_(1, 0); af[1][1] = RDA_(1, 1);
    if (t + 1 < NT) STAGEA(c ^ 1, 0, kb1);
    PH(0);
    // ---- ph2 ----
    af[0][0] = RDA_(2, 0); af[0][1] = RDA_(2, 1);
    af[1][0] = RDA_(3, 0); af[1][1] = RDA_(3, 1);
    if (t + 1 < NT) STAGEA(c ^ 1, 1, kb1);
    PH(1);
    __builtin_amdgcn_s_barrier();        // B-region recycle gate
    // ---- ph3 ----
    af[0][0] = RDA_(4, 0); af[0][1] = RDA_(4, 1);
    af[1][0] = RDA_(5, 0); af[1][1] = RDA_(5, 1);
    if (t + 2 < NT) STAGEB(c, 0, kb2);
    PH(2);
    // ---- ph4 ----
    af[0][0] = RDA_(6, 0); af[0][1] = RDA_(6, 1);
    af[1][0] = RDA_(7, 0); af[1][1] = RDA_(7, 1);
    if (t + 2 < NT) STAGEB(c, 1, kb2);
    PH(3);
  }

  // epilogue
  #pragma unroll
  for (int m = 0; m < 8; m++) {
    #pragma unroll
    for (int r = 0; r < 4; r++) {
      int grow = bm*256 + wm*128 + m*16 + g*4 + r;
      #pragma unroll
      for (int n = 0; n < NF; n++) {
        int gcol = bn*BN + wn*WN + n*16 + l15;
        float v = acc[m][n][r];
        if (BIAS) v += bias[gcol];
        if (GELU_) {
          float xx = v;
          float u = 0.7978845608f*(xx + 0.044715f*xx*xx*xx);
          float e = EXP2(u * 2.88539008f);
          float th = 1.0f - 2.0f*RCP(e + 1.0f);
          v = 0.5f*xx*(1.0f + th);
        }
        if (RESID) v += resid[(size_t)grow*N + gcol];
        if (OUTF32) ((float*)Cout)[(size_t)grow*N + gcol] = v;
        else ((unsigned short*)Cout)[(size_t)grow*N + gcol] = f2bf(v);
      }
    }
  }
#undef STAGEA
#undef STAGEB
#undef RDA_
#undef RDB_
#undef PH
}

// ---------------- causal flash attention ----------------
// 8 waves / 512 threads, QBLK=128 (wave owns 16 q-rows). Double-buffered K/V.
// Wq pre-scaled by log2(e)/sqrt(64) -> scores in exp2 domain. Defer-max (T13).
// LDS 48KB -> 3 blocks/CU = 24 waves/CU (vs 10 at the 4-wave version).
__global__ __launch_bounds__(512) void attn_kernel(
    const unsigned short* __restrict__ qb, const unsigned short* __restrict__ kb,
    const unsigned short* __restrict__ vt, unsigned short* __restrict__ ctx)
{
  __shared__ unsigned short sK[2][64*64];
  __shared__ unsigned short sV[2][64*64];
  __shared__ unsigned short sP[8][16*64];
  const int tid = threadIdx.x, wave = tid >> 6, lane = tid & 63;
  const int l15 = lane & 15, g = lane >> 4, x7 = lane & 7;
  const int qt = 15 - (blockIdx.x >> 6);      // heavy-first, QBLK=128
  const int bh = blockIdx.x & 63;
  const int b = bh >> 4, h = bh & 15;
  const int qrow = qt*128 + wave*16;
  const int NTI = 2*qt + 2;                   // KV tiles (64 each)

  bf16x8 qf[2];
  {
    const unsigned short* qr = qb + (size_t)(b*S_LEN + qrow + l15) * QKV_LD + h*64;
    qf[0] = *(const bf16x8*)&qr[g*8];
    qf[1] = *(const bf16x8*)&qr[32 + g*8];
  }

  f32x4 oacc[4] = {};
  float mrow[4], lrow[4];
  #pragma unroll
  for (int r = 0; r < 4; r++) { mrow[r] = -INFINITY; lrow[r] = 0.0f; }

  const int rrow = lane >> 3;
  const int srcc = (x7 ^ rrow) << 3;
  const unsigned short* kbase = kb + (size_t)(b*S_LEN)*QKV_LD + h*64 + srcc;
  const unsigned short* vbase = vt + (size_t)(bh*64)*S_LEN + srcc;

  // one GLD16 per wave for K, one for V: wave stages rows [wave*8, wave*8+8)
#define ASTAGE(buf, t) do { \
    const int kv0_ = (t)*64; \
    GLD16(kbase + (size_t)(kv0_ + wave*8 + rrow)*QKV_LD, &sK[buf][wave*8*64]); \
    GLD16(vbase + (size_t)(wave*8 + rrow)*S_LEN + kv0_,  &sV[buf][wave*8*64]); \
  } while(0)

  ASTAGE(0, 0);

  for (int t = 0; t < NTI; ++t) {
    __syncthreads();
    const int cur = t & 1;
    if (t < NTI - 1) ASTAGE(cur ^ 1, t + 1);

    const int kv0 = t*64;
    if (kv0 > qrow + 15) continue;   // fully-masked tile for this wave (waves 0-3, last tile)

    f32x4 sacc[4] = {};
    __builtin_amdgcn_s_setprio(1);
    #pragma unroll
    for (int kk = 0; kk < 2; kk++) {
      const int csw = ((kk*4 + g) ^ x7) << 3;
      #pragma unroll
      for (int n = 0; n < 4; n++) {
        bf16x8 kf = *(const bf16x8*)&sK[cur][(n*16 + l15)*64 + csw];
        sacc[n] = __builtin_amdgcn_mfma_f32_16x16x32_bf16(qf[kk], kf, sacc[n], 0, 0, 0);
      }
    }
    __builtin_amdgcn_s_setprio(0);

    float p[4][4], gm[4];
    const bool masked = (kv0 + 63 > qrow);
    #pragma unroll
    for (int r = 0; r < 4; r++) {
      float rm = -INFINITY;
      #pragma unroll
      for (int n = 0; n < 4; n++) {
        float sc = sacc[n][r];     // already log2-scaled via Wq
        if (masked && (kv0 + n*16 + l15) > (qrow + g*4 + r)) sc = -INFINITY;
        p[n][r] = sc;
        rm = fmaxf(rm, sc);
      }
      rm = fmaxf(rm, __shfl_xor(rm, 1));
      rm = fmaxf(rm, __shfl_xor(rm, 2));
      rm = fmaxf(rm, __shfl_xor(rm, 4));
      rm = fmaxf(rm, __shfl_xor(rm, 8));
      gm[r] = rm;
    }
    bool need = (gm[0] > mrow[0] + 8.0f) | (gm[1] > mrow[1] + 8.0f) |
                (gm[2] > mrow[2] + 8.0f) | (gm[3] > mrow[3] + 8.0f);
    if (__any(need)) {
      #pragma unroll
      for (int r = 0; r < 4; r++) {
        float mn = fmaxf(mrow[r], gm[r]);
        float alpha = EXP2(mrow[r] - mn);
        mrow[r] = mn;
        lrow[r] *= alpha;
        #pragma unroll
        for (int nd = 0; nd < 4; nd++) oacc[nd][r] *= alpha;
      }
    }
    #pragma unroll
    for (int r = 0; r < 4; r++) {
      float sum = 0.0f;
      #pragma unroll
      for (int n = 0; n < 4; n++) {
        float e = EXP2(p[n][r] - mrow[r]);
        p[n][r] = e;
        sum += e;
      }
      sum += __shfl_xor(sum, 1);
      sum += __shfl_xor(sum, 2);
      sum += __shfl_xor(sum, 4);
      sum += __shfl_xor(sum, 8);
      lrow[r] += sum;
    }

    #pragma unroll
    for (int n = 0; n < 4; n++) {
      const int chunk = n*2 + (l15 >> 3);
      #pragma unroll
      for (int r = 0; r < 4; r++) {
        const int prow = g*4 + r;
        sP[wave][prow*64 + ((chunk ^ (prow & 7)) << 3) + x7] = f2bf(p[n][r]);
      }
    }
    asm volatile("s_waitcnt lgkmcnt(0)" ::: "memory");
    __builtin_amdgcn_sched_barrier(0);

    __builtin_amdgcn_s_setprio(1);
    #pragma unroll
    for (int kk = 0; kk < 2; kk++) {
      const int csw = ((kk*4 + g) ^ x7) << 3;
      bf16x8 pa = *(const bf16x8*)&sP[wave][l15*64 + csw];
      #pragma unroll
      for (int nd = 0; nd < 4; nd++) {
        bf16x8 vf = *(const bf16x8*)&sV[cur][(nd*16 + l15)*64 + csw];
        oacc[nd] = __builtin_amdgcn_mfma_f32_16x16x32_bf16(pa, vf, oacc[nd], 0, 0, 0);
      }
    }
    __builtin_amdgcn_s_setprio(0);
  }

  #pragma unroll
  for (int r = 0; r < 4; r++) {
    float inv = 1.0f / lrow[r];
    size_t row = (size_t)(b*S_LEN + qrow + g*4 + r);
    #pragma unroll
    for (int nd = 0; nd < 4; nd++)
      ctx[row*DMODEL + h*64 + nd*16 + l15] = f2bf(oacc[nd][r] * inv);
  }
}

// ---------------- host ----------------
extern "C" void kernel_launch(void* const* d_in, const int* in_sizes, int n_in,
                              void* d_out, int out_size, void* d_ws, size_t ws_size,
                              hipStream_t stream)
{
  const float* x    = (const float*)d_in[0];
  const float* Wq   = (const float*)d_in[1];
  const float* Wk   = (const float*)d_in[2];
  const float* Wv   = (const float*)d_in[3];
  const float* Wo   = (const float*)d_in[4];
  const float* bo   = (const float*)d_in[5];
  const float* W1   = (const float*)d_in[6];
  const float* b1   = (const float*)d_in[7];
  const float* W2   = (const float*)d_in[8];
  const float* b2   = (const float*)d_in[9];
  const float* ln1s = (const float*)d_in[10];
  const float* ln1b = (const float*)d_in[11];
  const float* ln2s = (const float*)d_in[12];
  const float* ln2b = (const float*)d_in[13];
  float* out = (float*)d_out;
  (void)in_sizes; (void)n_in; (void)out_size; (void)ws_size;

  char* ws = (char*)d_ws;
  size_t off = 0;
  auto alloc = [&](size_t n) { char* p = ws + off; off += (n + 255) & ~(size_t)255; return p; };
  unsigned short* hbuf  = (unsigned short*)alloc((size_t)NROWS*DMODEL*2);
  unsigned short* qkv   = (unsigned short*)alloc((size_t)NROWS*QKV_LD*2);
  unsigned short* vtb   = (unsigned short*)alloc((size_t)NROWS*DMODEL*2);
  unsigned short* ctx   = (unsigned short*)alloc((size_t)NROWS*DMODEL*2);
  unsigned short* ffn1  = (unsigned short*)alloc((size_t)NROWS*DFF*2);
  unsigned short* wqkvt = (unsigned short*)alloc((size_t)QKV_LD*DMODEL*2);
  unsigned short* wot   = (unsigned short*)alloc((size_t)DMODEL*DMODEL*2);
  unsigned short* w1t   = (unsigned short*)alloc((size_t)DFF*DMODEL*2);
  unsigned short* w2t   = (unsigned short*)alloc((size_t)DMODEL*DFF*2);

  const float SCLQ = 0.18033688011f;  // log2(e)/sqrt(64)

  wtrans_all<<<dim3(3072), dim3(256), 0, stream>>>(
      Wq, Wk, Wv, Wo, W1, W2, wqkvt, wot, w1t, w2t, SCLQ);

  // LN1
  ln_kernel<<<dim3(NROWS), dim3(256), 0, stream>>>(x, ln1s, ln1b, hbuf);
  // fused QKV projection
  gemm256<256,false,false,false,false><<<dim3(32*12), dim3(512), 0, stream>>>(
      hbuf, wqkvt, (void*)qkv, nullptr, nullptr, NROWS, QKV_LD, DMODEL);
  // V^T
  vtrans<<<dim3(2048), dim3(256), 0, stream>>>(qkv + 2048, vtb);
  // attention (8-wave, QBLK=128)
  attn_kernel<<<dim3(1024), dim3(512), 0, stream>>>(qkv, qkv + 1024, vtb, ctx);
  // out proj + bo + residual(x) -> d_out fp32
  gemm256<128,true,false,true,true><<<dim3(32*8), dim3(512), 0, stream>>>(
      ctx, wot, (void*)out, bo, x, NROWS, DMODEL, DMODEL);
  // LN2
  ln_kernel<<<dim3(NROWS), dim3(256), 0, stream>>>(out, ln2s, ln2b, hbuf);
  // FFN1 + b1 + GELU -> bf16
  gemm256<256,true,true,false,false><<<dim3(32*16), dim3(512), 0, stream>>>(
      hbuf, w1t, (void*)ffn1, b1, nullptr, NROWS, DFF, DMODEL);
  // FFN2 + b2 + residual(d_out) -> d_out fp32
  gemm256<128,true,false,true,true><<<dim3(32*8), dim3(512), 0, stream>>>(
      ffn1, w2t, (void*)out, b2, out, NROWS, DMODEL, DFF);
}

// Round 6
// 370.991 us; speedup vs baseline: 7.0444x; 1.1663x over previous
//
#include <hip/hip_runtime.h>
#include <math.h>

// ---- problem constants ----
#define S_LEN  2048
#define DMODEL 1024
#define NHEAD  16
#define BATCH  4
#define NROWS  (BATCH*S_LEN)   // 8192
#define DFF    4096
#define QKV_LD 3072            // fused q|k|v row stride

typedef __attribute__((ext_vector_type(4))) unsigned short us4;
typedef __attribute__((ext_vector_type(8))) unsigned short us8;
typedef __attribute__((ext_vector_type(8))) __bf16 bf16x8;
typedef __attribute__((ext_vector_type(4))) float f32x4;

#if __has_builtin(__builtin_amdgcn_exp2f)
#define EXP2(x) __builtin_amdgcn_exp2f(x)
#else
#define EXP2(x) exp2f(x)
#endif
#if __has_builtin(__builtin_amdgcn_rcpf)
#define RCP(x) __builtin_amdgcn_rcpf(x)
#else
#define RCP(x) (1.0f/(x))
#endif

static __device__ __forceinline__ unsigned short f2bf(float f) {
  __bf16 b = (__bf16)f;                       // HW RNE convert on gfx950
  return __builtin_bit_cast(unsigned short, b);
}
#define GLD16(gp, lp) __builtin_amdgcn_global_load_lds( \
    (const __attribute__((address_space(1))) unsigned int*)(gp), \
    (__attribute__((address_space(3))) unsigned int*)(lp), 16, 0, 0)

// XCD-aware bijective block swizzle (requires gridDim.x % 8 == 0)
static __device__ __forceinline__ int xcd_swz(int bid, int nwg) {
  int q = nwg >> 3;
  return (bid & 7) * q + (bid >> 3);
}

// ---------------- LayerNorm: fp32 in -> bf16 out ----------------
__global__ __launch_bounds__(256) void ln_kernel(
    const float* __restrict__ x, const float* __restrict__ scale,
    const float* __restrict__ shift, unsigned short* __restrict__ out)
{
  const int row = blockIdx.x, tid = threadIdx.x;
  const int lane = tid & 63, wave = tid >> 6;
  const float* xr = x + (size_t)row * DMODEL;
  f32x4 v = *(const f32x4*)&xr[tid * 4];
  float s  = v[0]+v[1]+v[2]+v[3];
  float s2 = v[0]*v[0]+v[1]*v[1]+v[2]*v[2]+v[3]*v[3];
  #pragma unroll
  for (int m = 1; m < 64; m <<= 1) { s += __shfl_xor(s, m); s2 += __shfl_xor(s2, m); }
  __shared__ float red[8];
  if (lane == 0) { red[wave] = s; red[4 + wave] = s2; }
  __syncthreads();
  s  = red[0]+red[1]+red[2]+red[3];
  s2 = red[4]+red[5]+red[6]+red[7];
  float mean = s * (1.0f/DMODEL);
  float var  = s2 * (1.0f/DMODEL) - mean*mean;
  float rstd = rsqrtf(var + 1e-5f);
  us4 o;
  #pragma unroll
  for (int j = 0; j < 4; j++) {
    float val = (v[j]-mean)*rstd*scale[tid*4+j] + shift[tid*4+j];
    o[j] = f2bf(val);
  }
  *(us4*)&out[(size_t)row*DMODEL + tid*4] = o;
}

// ------- merged weight convert+transpose: all 6 weights in one launch -------
__global__ __launch_bounds__(256) void wtrans_all(
    const float* __restrict__ Wq, const float* __restrict__ Wk,
    const float* __restrict__ Wv, const float* __restrict__ Wo,
    const float* __restrict__ W1, const float* __restrict__ W2,
    unsigned short* __restrict__ wqkvt, unsigned short* __restrict__ wot,
    unsigned short* __restrict__ w1t, unsigned short* __restrict__ w2t,
    float sclq)
{
  __shared__ unsigned short tile[64][72];
  const int bid = blockIdx.x, tid = threadIdx.x;
  const float* W; unsigned short* Wt; int K, N, sub; float scl = 1.0f;
  if (bid < 1024) {
    int wsel = bid >> 8; sub = bid & 255; K = 1024; N = 1024;
    W  = (wsel == 0) ? Wq : (wsel == 1) ? Wk : (wsel == 2) ? Wv : Wo;
    Wt = (wsel == 0) ? wqkvt : (wsel == 1) ? wqkvt + 1024*1024
       : (wsel == 2) ? wqkvt + 2048*1024 : wot;
    if (wsel == 0) scl = sclq;
  } else if (bid < 2048) { sub = bid - 1024; K = 1024; N = 4096; W = W1; Wt = w1t; }
  else                   { sub = bid - 2048; K = 4096; N = 1024; W = W2; Wt = w2t; }
  const int nbn = N >> 6;
  const int kt = sub / nbn, nt = sub % nbn;
  int r = tid >> 2, c0 = (tid & 3) << 4;
  const float* src = W + (size_t)(kt*64 + r)*N + nt*64 + c0;
  #pragma unroll
  for (int j = 0; j < 16; j += 4) {
    f32x4 f = *(const f32x4*)&src[j];
    tile[r][c0+j+0] = f2bf(f[0]*scl); tile[r][c0+j+1] = f2bf(f[1]*scl);
    tile[r][c0+j+2] = f2bf(f[2]*scl); tile[r][c0+j+3] = f2bf(f[3]*scl);
  }
  __syncthreads();
  int n = tid >> 2, k0 = (tid & 3) << 4;
  us8 o0, o1;
  #pragma unroll
  for (int j = 0; j < 8; j++) { o0[j] = tile[k0+j][n]; o1[j] = tile[k0+8+j][n]; }
  unsigned short* dst = Wt + (size_t)(nt*64 + n)*K + kt*64 + k0;
  *(us8*)&dst[0] = o0;
  *(us8*)&dst[8] = o1;
}

// ------- V transpose: v rows [B*S][QKV_LD] (v section) -> vt[(b*H+h)*64+d][S] -------
__global__ __launch_bounds__(256) void vtrans(
    const unsigned short* __restrict__ v, unsigned short* __restrict__ vt)
{
  __shared__ unsigned short tile[64][72];
  const int tid = threadIdx.x;
  const int bh = blockIdx.x >> 5, st = blockIdx.x & 31;
  const int b = bh >> 4, h = bh & 15;
  int r = tid >> 2, c0 = (tid & 3) << 4;
  const unsigned short* src = v + (size_t)(b*S_LEN + st*64 + r)*QKV_LD + h*64 + c0;
  *(us8*)&tile[r][c0]   = *(const us8*)&src[0];
  *(us8*)&tile[r][c0+8] = *(const us8*)&src[8];
  __syncthreads();
  int d = tid >> 2, s0 = (tid & 3) << 4;
  us8 o0, o1;
  #pragma unroll
  for (int j = 0; j < 8; j++) { o0[j] = tile[s0+j][d]; o1[j] = tile[s0+8+j][d]; }
  unsigned short* dst = vt + (size_t)(bh*64 + d)*S_LEN + st*64 + s0;
  *(us8*)&dst[0] = o0;
  *(us8*)&dst[8] = o1;
}

// ---------------- 128x128 GEMM (Wo / FFN2): proven m97-class ----------------
template<bool BIAS, bool RESID, bool GELU_, bool OUTF32>
__global__ __launch_bounds__(256, 3) void gemm_bt(
    const unsigned short* __restrict__ A, const unsigned short* __restrict__ Bt,
    void* Cout, const float* __restrict__ bias, const float* resid,
    int M, int N, int K)
{
  __shared__ unsigned short sA[128*64];
  __shared__ unsigned short sB[128*64];
  const int tid = threadIdx.x;
  const int wave = tid >> 6, lane = tid & 63;
  const int l15 = lane & 15, g = lane >> 4, x7 = lane & 7;
  const int nbn = N >> 7;
  const int bid = xcd_swz(blockIdx.x, gridDim.x);
  const int bm = bid / nbn, bn = bid % nbn;
  const int wr = (wave >> 1) << 6, wc = (wave & 1) << 6;

  f32x4 acc[4][4] = {};

  const int rrow = lane >> 3;
  const int srcc = (x7 ^ rrow) << 3;           // pre-swizzled source chunk
  const unsigned short* ga0 = A  + (size_t)(bm*128 + rrow)*K + srcc;
  const unsigned short* gb0 = Bt + (size_t)(bn*128 + rrow)*K + srcc;

  for (int kb = 0; kb < K; kb += 64) {
    #pragma unroll
    for (int i = 0; i < 4; i++) {
      int rr = (wave*4 + i) * 8;
      GLD16(ga0 + (size_t)rr*K + kb, &sA[rr*64]);
      GLD16(gb0 + (size_t)rr*K + kb, &sB[rr*64]);
    }
    __syncthreads();
    #pragma unroll
    for (int kk = 0; kk < 2; kk++) {
      const int csw = ((kk*4 + g) ^ x7) << 3;
      bf16x8 af[4], bfr[4];
      #pragma unroll
      for (int m = 0; m < 4; m++)
        af[m] = *(const bf16x8*)&sA[(wr + m*16 + l15)*64 + csw];
      #pragma unroll
      for (int n = 0; n < 4; n++)
        bfr[n] = *(const bf16x8*)&sB[(wc + n*16 + l15)*64 + csw];
      #pragma unroll
      for (int m = 0; m < 4; m++)
        #pragma unroll
        for (int n = 0; n < 4; n++)
          acc[m][n] = __builtin_amdgcn_mfma_f32_16x16x32_bf16(af[m], bfr[n], acc[m][n], 0, 0, 0);
    }
    __syncthreads();
  }

  #pragma unroll
  for (int m = 0; m < 4; m++) {
    #pragma unroll
    for (int r = 0; r < 4; r++) {
      int grow = bm*128 + wr + m*16 + g*4 + r;
      #pragma unroll
      for (int n = 0; n < 4; n++) {
        int gcol = bn*128 + wc + n*16 + l15;
        float v = acc[m][n][r];
        if (BIAS) v += bias[gcol];
        if (GELU_) {
          float xx = v;
          float u = 0.7978845608f*(xx + 0.044715f*xx*xx*xx);
          float e = EXP2(u * 2.88539008f);
          float th = 1.0f - 2.0f*RCP(e + 1.0f);
          v = 0.5f*xx*(1.0f + th);
        }
        if (RESID) v += resid[(size_t)grow*N + gcol];
        if (OUTF32) ((float*)Cout)[(size_t)grow*N + gcol] = v;
        else ((unsigned short*)Cout)[(size_t)grow*N + gcol] = f2bf(v);
      }
    }
  }
}

// ------- 256x256 pipelined GEMM (QKV / FFN1) -------
template<bool BIAS, bool GELU_>
__global__ __launch_bounds__(512, 2) void gemm256(
    const unsigned short* __restrict__ A, const unsigned short* __restrict__ Bt,
    unsigned short* __restrict__ Cout, const float* __restrict__ bias,
    int M, int N, int K)
{
  constexpr int BN = 256, WN = 64, NF = 4;
  __shared__ unsigned short sA[2][256*64];
  __shared__ unsigned short sB[2][BN*64];
  const int tid = threadIdx.x;
  const int wave = tid >> 6, lane = tid & 63;
  const int wm = wave >> 2, wn = wave & 3;
  const int l15 = lane & 15, g = lane >> 4, x7 = lane & 7, r8 = lane >> 3;
  const int srcc = (x7 ^ r8) << 3;
  const int nbn = N / BN;
  const int bid = xcd_swz(blockIdx.x, gridDim.x);
  const int bm = bid / nbn, bn = bid % nbn;
  const unsigned short* gA = A  + (size_t)(bm*256)*K;
  const unsigned short* gB = Bt + (size_t)(bn*BN)*K;
  const int NT = K >> 6;

  f32x4 acc[8][NF] = {};

#define STAGEA(buf, h, kb) do { \
    _Pragma("unroll") \
    for (int j_ = 0; j_ < 2; j_++) \
      GLD16(gA + (size_t)((h)*128 + j_*64 + wave*8 + r8)*K + (kb) + srcc, \
            &sA[buf][((h)*128 + j_*64 + wave*8)*64]); \
  } while (0)
#define STAGEB(buf, h, kb) do { \
    _Pragma("unroll") \
    for (int j_ = 0; j_ < 2; j_++) \
      GLD16(gB + (size_t)((h)*128 + j_*64 + wave*8 + r8)*K + (kb) + srcc, \
            &sB[buf][((h)*128 + j_*64 + wave*8)*64]); \
  } while (0)
#define RDA_(m, kk) (*(const bf16x8*)&cA[(wm*128 + (m)*16 + l15)*64 + ((((kk)*4+g)^x7)<<3)])
#define RDB_(n, kk) (*(const bf16x8*)&cB[(wn*WN + (n)*16 + l15)*64 + ((((kk)*4+g)^x7)<<3)])
#define PH(p) do { \
    __builtin_amdgcn_s_setprio(1); \
    _Pragma("unroll") for (int mm_ = 0; mm_ < 2; mm_++) \
    _Pragma("unroll") for (int n_ = 0; n_ < NF; n_++) \
    _Pragma("unroll") for (int kk_ = 0; kk_ < 2; kk_++) \
      acc[(p)*2+mm_][n_] = __builtin_amdgcn_mfma_f32_16x16x32_bf16( \
          af[mm_][kk_], bfr[n_][kk_], acc[(p)*2+mm_][n_], 0, 0, 0); \
    __builtin_amdgcn_s_setprio(0); \
  } while (0)

  // prologue: B(0),A(0) -> buf0 ; B(1) -> buf1
  STAGEB(0, 0, 0); STAGEB(0, 1, 0);
  STAGEA(0, 0, 0); STAGEA(0, 1, 0);
  STAGEB(1, 0, 64); STAGEB(1, 1, 64);

  for (int t = 0; t < NT; ++t) {
    const int c = t & 1;
    const unsigned short* cA = sA[c];
    const unsigned short* cB = sB[c];
    const int kb1 = (t + 1) * 64, kb2 = (t + 2) * 64;
    bf16x8 af[2][2], bfr[NF][2];

    if (t < NT - 1) asm volatile("s_waitcnt vmcnt(4)" ::: "memory");
    else            asm volatile("s_waitcnt vmcnt(0)" ::: "memory");
    __builtin_amdgcn_s_barrier();
    __builtin_amdgcn_sched_barrier(0);

    // ---- ph1: B reg-cache + A m0,m1 ----
    #pragma unroll
    for (int n = 0; n < NF; n++) { bfr[n][0] = RDB_(n, 0); bfr[n][1] = RDB_(n, 1); }
    af[0][0] = RDA_(0, 0); af[0][1] = RDA_(0, 1);
    af[1][0] = RDA_(1, 0); af[1][1] = RDA_(1, 1);
    if (t + 1 < NT) STAGEA(c ^ 1, 0, kb1);
    PH(0);
    // ---- ph2 ----
    af[0][0] = RDA_(2, 0); af[0][1] = RDA_(2, 1);
    af[1][0] = RDA_(3, 0); af[1][1] = RDA_(3, 1);
    if (t + 1 < NT) STAGEA(c ^ 1, 1, kb1);
    PH(1);
    __builtin_amdgcn_s_barrier();        // B-region recycle gate
    // ---- ph3 ----
    af[0][0] = RDA_(4, 0); af[0][1] = RDA_(4, 1);
    af[1][0] = RDA_(5, 0); af[1][1] = RDA_(5, 1);
    if (t + 2 < NT) STAGEB(c, 0, kb2);
    PH(2);
    // ---- ph4 ----
    af[0][0] = RDA_(6, 0); af[0][1] = RDA_(6, 1);
    af[1][0] = RDA_(7, 0); af[1][1] = RDA_(7, 1);
    if (t + 2 < NT) STAGEB(c, 1, kb2);
    PH(3);
  }

  // epilogue
  #pragma unroll
  for (int m = 0; m < 8; m++) {
    #pragma unroll
    for (int r = 0; r < 4; r++) {
      int grow = bm*256 + wm*128 + m*16 + g*4 + r;
      #pragma unroll
      for (int n = 0; n < NF; n++) {
        int gcol = bn*BN + wn*WN + n*16 + l15;
        float v = acc[m][n][r];
        if (BIAS) v += bias[gcol];
        if (GELU_) {
          float xx = v;
          float u = 0.7978845608f*(xx + 0.044715f*xx*xx*xx);
          float e = EXP2(u * 2.88539008f);
          float th = 1.0f - 2.0f*RCP(e + 1.0f);
          v = 0.5f*xx*(1.0f + th);
        }
        Cout[(size_t)grow*N + gcol] = f2bf(v);
      }
    }
  }
#undef STAGEA
#undef STAGEB
#undef RDA_
#undef RDB_
#undef PH
}

// ---------------- causal flash attention ----------------
// 8 waves / QBLK=128. Ones-column MFMA computes softmax denominator (no sum
// shuffles); max-reduce deferred behind a per-lane ballot (T13). exp2 domain.
__global__ __launch_bounds__(512) void attn_kernel(
    const unsigned short* __restrict__ qb, const unsigned short* __restrict__ kb,
    const unsigned short* __restrict__ vt, unsigned short* __restrict__ ctx)
{
  __shared__ unsigned short sK[2][64*64];
  __shared__ unsigned short sV[2][64*64];
  __shared__ unsigned short sP[8][16*64];
  const int tid = threadIdx.x, wave = tid >> 6, lane = tid & 63;
  const int l15 = lane & 15, g = lane >> 4, x7 = lane & 7;
  const int qt = 15 - (blockIdx.x >> 6);      // heavy-first, QBLK=128
  const int bh = blockIdx.x & 63;
  const int b = bh >> 4, h = bh & 15;
  const int qrow = qt*128 + wave*16;
  const int NTI = 2*qt + 2;                   // KV tiles (64 each)

  bf16x8 qf[2];
  {
    const unsigned short* qr = qb + (size_t)(b*S_LEN + qrow + l15) * QKV_LD + h*64;
    qf[0] = *(const bf16x8*)&qr[g*8];
    qf[1] = *(const bf16x8*)&qr[32 + g*8];
  }

  // all-ones bf16 fragment for the denominator MFMA
  us8 ones_u;
  #pragma unroll
  for (int j = 0; j < 8; j++) ones_u[j] = 0x3F80;
  const bf16x8 ones8 = __builtin_bit_cast(bf16x8, ones_u);

  f32x4 oacc[4] = {};
  f32x4 lacc = {};
  float mrow[4];
  #pragma unroll
  for (int r = 0; r < 4; r++) mrow[r] = -INFINITY;

  const int rrow = lane >> 3;
  const int srcc = (x7 ^ rrow) << 3;
  const unsigned short* kbase = kb + (size_t)(b*S_LEN)*QKV_LD + h*64 + srcc;
  const unsigned short* vbase = vt + (size_t)(bh*64)*S_LEN + srcc;

#define ASTAGE(buf, t) do { \
    const int kv0_ = (t)*64; \
    GLD16(kbase + (size_t)(kv0_ + wave*8 + rrow)*QKV_LD, &sK[buf][wave*8*64]); \
    GLD16(vbase + (size_t)(wave*8 + rrow)*S_LEN + kv0_,  &sV[buf][wave*8*64]); \
  } while(0)

  ASTAGE(0, 0);

  for (int t = 0; t < NTI; ++t) {
    __syncthreads();
    const int cur = t & 1;
    if (t < NTI - 1) ASTAGE(cur ^ 1, t + 1);

    const int kv0 = t*64;
    if (kv0 > qrow + 15) continue;   // fully-masked tile for this wave

    f32x4 sacc[4] = {};
    __builtin_amdgcn_s_setprio(1);
    #pragma unroll
    for (int kk = 0; kk < 2; kk++) {
      const int csw = ((kk*4 + g) ^ x7) << 3;
      #pragma unroll
      for (int n = 0; n < 4; n++) {
        bf16x8 kf = *(const bf16x8*)&sK[cur][(n*16 + l15)*64 + csw];
        sacc[n] = __builtin_amdgcn_mfma_f32_16x16x32_bf16(qf[kk], kf, sacc[n], 0, 0, 0);
      }
    }
    __builtin_amdgcn_s_setprio(0);

    float p[4][4], rm[4];
    const bool masked = (kv0 + 63 > qrow);
    #pragma unroll
    for (int r = 0; r < 4; r++) {
      float m_ = -INFINITY;
      #pragma unroll
      for (int n = 0; n < 4; n++) {
        float sc = sacc[n][r];     // already log2-scaled via Wq
        if (masked && (kv0 + n*16 + l15) > (qrow + g*4 + r)) sc = -INFINITY;
        p[n][r] = sc;
        m_ = fmaxf(m_, sc);
      }
      rm[r] = m_;
    }
    // defer-max: full 16-lane reduce + rescale only when a lane max exceeds
    bool need = (rm[0] > mrow[0] + 8.0f) | (rm[1] > mrow[1] + 8.0f) |
                (rm[2] > mrow[2] + 8.0f) | (rm[3] > mrow[3] + 8.0f);
    if (__any(need)) {
      #pragma unroll
      for (int r = 0; r < 4; r++) {
        float vv = rm[r];
        vv = fmaxf(vv, __shfl_xor(vv, 1));
        vv = fmaxf(vv, __shfl_xor(vv, 2));
        vv = fmaxf(vv, __shfl_xor(vv, 4));
        vv = fmaxf(vv, __shfl_xor(vv, 8));
        float mn = fmaxf(mrow[r], vv);
        float alpha = EXP2(mrow[r] - mn);
        mrow[r] = mn;
        lacc[r] *= alpha;
        #pragma unroll
        for (int nd = 0; nd < 4; nd++) oacc[nd][r] *= alpha;
      }
    }
    #pragma unroll
    for (int n = 0; n < 4; n++)
      #pragma unroll
      for (int r = 0; r < 4; r++)
        p[n][r] = EXP2(p[n][r] - mrow[r]);

    #pragma unroll
    for (int n = 0; n < 4; n++) {
      const int chunk = n*2 + (l15 >> 3);
      #pragma unroll
      for (int r = 0; r < 4; r++) {
        const int prow = g*4 + r;
        sP[wave][prow*64 + ((chunk ^ (prow & 7)) << 3) + x7] = f2bf(p[n][r]);
      }
    }
    asm volatile("s_waitcnt lgkmcnt(0)" ::: "memory");
    __builtin_amdgcn_sched_barrier(0);

    __builtin_amdgcn_s_setprio(1);
    #pragma unroll
    for (int kk = 0; kk < 2; kk++) {
      const int csw = ((kk*4 + g) ^ x7) << 3;
      bf16x8 pa = *(const bf16x8*)&sP[wave][l15*64 + csw];
      #pragma unroll
      for (int nd = 0; nd < 4; nd++) {
        bf16x8 vf = *(const bf16x8*)&sV[cur][(nd*16 + l15)*64 + csw];
        oacc[nd] = __builtin_amdgcn_mfma_f32_16x16x32_bf16(pa, vf, oacc[nd], 0, 0, 0);
      }
      lacc = __builtin_amdgcn_mfma_f32_16x16x32_bf16(pa, ones8, lacc, 0, 0, 0);
    }
    __builtin_amdgcn_s_setprio(0);
  }

  #pragma unroll
  for (int r = 0; r < 4; r++) {
    float inv = RCP(lacc[r]);
    size_t row = (size_t)(b*S_LEN + qrow + g*4 + r);
    #pragma unroll
    for (int nd = 0; nd < 4; nd++)
      ctx[row*DMODEL + h*64 + nd*16 + l15] = f2bf(oacc[nd][r] * inv);
  }
}

// ---------------- host ----------------
extern "C" void kernel_launch(void* const* d_in, const int* in_sizes, int n_in,
                              void* d_out, int out_size, void* d_ws, size_t ws_size,
                              hipStream_t stream)
{
  const float* x    = (const float*)d_in[0];
  const float* Wq   = (const float*)d_in[1];
  const float* Wk   = (const float*)d_in[2];
  const float* Wv   = (const float*)d_in[3];
  const float* Wo   = (const float*)d_in[4];
  const float* bo   = (const float*)d_in[5];
  const float* W1   = (const float*)d_in[6];
  const float* b1   = (const float*)d_in[7];
  const float* W2   = (const float*)d_in[8];
  const float* b2   = (const float*)d_in[9];
  const float* ln1s = (const float*)d_in[10];
  const float* ln1b = (const float*)d_in[11];
  const float* ln2s = (const float*)d_in[12];
  const float* ln2b = (const float*)d_in[13];
  float* out = (float*)d_out;
  (void)in_sizes; (void)n_in; (void)out_size; (void)ws_size;

  char* ws = (char*)d_ws;
  size_t off = 0;
  auto alloc = [&](size_t n) { char* p = ws + off; off += (n + 255) & ~(size_t)255; return p; };
  unsigned short* hbuf  = (unsigned short*)alloc((size_t)NROWS*DMODEL*2);
  unsigned short* qkv   = (unsigned short*)alloc((size_t)NROWS*QKV_LD*2);
  unsigned short* vtb   = (unsigned short*)alloc((size_t)NROWS*DMODEL*2);
  unsigned short* ctx   = (unsigned short*)alloc((size_t)NROWS*DMODEL*2);
  unsigned short* ffn1  = (unsigned short*)alloc((size_t)NROWS*DFF*2);
  unsigned short* wqkvt = (unsigned short*)alloc((size_t)QKV_LD*DMODEL*2);
  unsigned short* wot   = (unsigned short*)alloc((size_t)DMODEL*DMODEL*2);
  unsigned short* w1t   = (unsigned short*)alloc((size_t)DFF*DMODEL*2);
  unsigned short* w2t   = (unsigned short*)alloc((size_t)DMODEL*DFF*2);

  const float SCLQ = 0.18033688011f;  // log2(e)/sqrt(64)

  wtrans_all<<<dim3(3072), dim3(256), 0, stream>>>(
      Wq, Wk, Wv, Wo, W1, W2, wqkvt, wot, w1t, w2t, SCLQ);

  // LN1
  ln_kernel<<<dim3(NROWS), dim3(256), 0, stream>>>(x, ln1s, ln1b, hbuf);
  // fused QKV projection
  gemm256<false,false><<<dim3(32*12), dim3(512), 0, stream>>>(
      hbuf, wqkvt, qkv, nullptr, NROWS, QKV_LD, DMODEL);
  // V^T
  vtrans<<<dim3(2048), dim3(256), 0, stream>>>(qkv + 2048, vtb);
  // attention (8-wave, QBLK=128)
  attn_kernel<<<dim3(1024), dim3(512), 0, stream>>>(qkv, qkv + 1024, vtb, ctx);
  // out proj + bo + residual(x) -> d_out fp32
  gemm_bt<true,true,false,true><<<dim3(64*8), dim3(256), 0, stream>>>(
      ctx, wot, (void*)out, bo, x, NROWS, DMODEL, DMODEL);
  // LN2
  ln_kernel<<<dim3(NROWS), dim3(256), 0, stream>>>(out, ln2s, ln2b, hbuf);
  // FFN1 + b1 + GELU -> bf16
  gemm256<true,true><<<dim3(32*16), dim3(512), 0, stream>>>(
      hbuf, w1t, ffn1, b1, NROWS, DFF, DMODEL);
  // FFN2 + b2 + residual(d_out) -> d_out fp32
  gemm_bt<true,true,false,true><<<dim3(64*8), dim3(256), 0, stream>>>(
      ffn1, w2t, (void*)out, b2, out, NROWS, DMODEL, DFF);
}

// Round 7
// 357.434 us; speedup vs baseline: 7.3116x; 1.0379x over previous
//
#include <hip/hip_runtime.h>
#include <math.h>

// ---- problem constants ----
#define S_LEN  2048
#define DMODEL 1024
#define NHEAD  16
#define BATCH  4
#define NROWS  (BATCH*S_LEN)   // 8192
#define DFF    4096
#define QKV_LD 3072            // fused q|k|v row stride

typedef __attribute__((ext_vector_type(4))) unsigned short us4;
typedef __attribute__((ext_vector_type(8))) unsigned short us8;
typedef __attribute__((ext_vector_type(8))) __bf16 bf16x8;
typedef __attribute__((ext_vector_type(4))) float f32x4;

#if __has_builtin(__builtin_amdgcn_exp2f)
#define EXP2(x) __builtin_amdgcn_exp2f(x)
#else
#define EXP2(x) exp2f(x)
#endif
#if __has_builtin(__builtin_amdgcn_rcpf)
#define RCP(x) __builtin_amdgcn_rcpf(x)
#else
#define RCP(x) (1.0f/(x))
#endif

static __device__ __forceinline__ unsigned short f2bf(float f) {
  __bf16 b = (__bf16)f;                       // HW RNE convert on gfx950
  return __builtin_bit_cast(unsigned short, b);
}
#define GLD16(gp, lp) __builtin_amdgcn_global_load_lds( \
    (const __attribute__((address_space(1))) unsigned int*)(gp), \
    (__attribute__((address_space(3))) unsigned int*)(lp), 16, 0, 0)

// XCD-aware bijective block swizzle (requires gridDim.x % 8 == 0)
static __device__ __forceinline__ int xcd_swz(int bid, int nwg) {
  int q = nwg >> 3;
  return (bid & 7) * q + (bid >> 3);
}

// ---------------- LayerNorm: fp32 in -> bf16 out ----------------
__global__ __launch_bounds__(256) void ln_kernel(
    const float* __restrict__ x, const float* __restrict__ scale,
    const float* __restrict__ shift, unsigned short* __restrict__ out)
{
  const int row = blockIdx.x, tid = threadIdx.x;
  const int lane = tid & 63, wave = tid >> 6;
  const float* xr = x + (size_t)row * DMODEL;
  f32x4 v = *(const f32x4*)&xr[tid * 4];
  float s  = v[0]+v[1]+v[2]+v[3];
  float s2 = v[0]*v[0]+v[1]*v[1]+v[2]*v[2]+v[3]*v[3];
  #pragma unroll
  for (int m = 1; m < 64; m <<= 1) { s += __shfl_xor(s, m); s2 += __shfl_xor(s2, m); }
  __shared__ float red[8];
  if (lane == 0) { red[wave] = s; red[4 + wave] = s2; }
  __syncthreads();
  s  = red[0]+red[1]+red[2]+red[3];
  s2 = red[4]+red[5]+red[6]+red[7];
  float mean = s * (1.0f/DMODEL);
  float var  = s2 * (1.0f/DMODEL) - mean*mean;
  float rstd = rsqrtf(var + 1e-5f);
  us4 o;
  #pragma unroll
  for (int j = 0; j < 4; j++) {
    float val = (v[j]-mean)*rstd*scale[tid*4+j] + shift[tid*4+j];
    o[j] = f2bf(val);
  }
  *(us4*)&out[(size_t)row*DMODEL + tid*4] = o;
}

// ------- merged weight convert+transpose: all 6 weights in one launch -------
__global__ __launch_bounds__(256) void wtrans_all(
    const float* __restrict__ Wq, const float* __restrict__ Wk,
    const float* __restrict__ Wv, const float* __restrict__ Wo,
    const float* __restrict__ W1, const float* __restrict__ W2,
    unsigned short* __restrict__ wqkvt, unsigned short* __restrict__ wot,
    unsigned short* __restrict__ w1t, unsigned short* __restrict__ w2t,
    float sclq)
{
  __shared__ unsigned short tile[64][72];
  const int bid = blockIdx.x, tid = threadIdx.x;
  const float* W; unsigned short* Wt; int K, N, sub; float scl = 1.0f;
  if (bid < 1024) {
    int wsel = bid >> 8; sub = bid & 255; K = 1024; N = 1024;
    W  = (wsel == 0) ? Wq : (wsel == 1) ? Wk : (wsel == 2) ? Wv : Wo;
    Wt = (wsel == 0) ? wqkvt : (wsel == 1) ? wqkvt + 1024*1024
       : (wsel == 2) ? wqkvt + 2048*1024 : wot;
    if (wsel == 0) scl = sclq;
  } else if (bid < 2048) { sub = bid - 1024; K = 1024; N = 4096; W = W1; Wt = w1t; }
  else                   { sub = bid - 2048; K = 4096; N = 1024; W = W2; Wt = w2t; }
  const int nbn = N >> 6;
  const int kt = sub / nbn, nt = sub % nbn;
  int r = tid >> 2, c0 = (tid & 3) << 4;
  const float* src = W + (size_t)(kt*64 + r)*N + nt*64 + c0;
  #pragma unroll
  for (int j = 0; j < 16; j += 4) {
    f32x4 f = *(const f32x4*)&src[j];
    tile[r][c0+j+0] = f2bf(f[0]*scl); tile[r][c0+j+1] = f2bf(f[1]*scl);
    tile[r][c0+j+2] = f2bf(f[2]*scl); tile[r][c0+j+3] = f2bf(f[3]*scl);
  }
  __syncthreads();
  int n = tid >> 2, k0 = (tid & 3) << 4;
  us8 o0, o1;
  #pragma unroll
  for (int j = 0; j < 8; j++) { o0[j] = tile[k0+j][n]; o1[j] = tile[k0+8+j][n]; }
  unsigned short* dst = Wt + (size_t)(nt*64 + n)*K + kt*64 + k0;
  *(us8*)&dst[0] = o0;
  *(us8*)&dst[8] = o1;
}

// ------- V transpose: v rows [B*S][QKV_LD] (v section) -> vt[(b*H+h)*64+d][S] -------
__global__ __launch_bounds__(256) void vtrans(
    const unsigned short* __restrict__ v, unsigned short* __restrict__ vt)
{
  __shared__ unsigned short tile[64][72];
  const int tid = threadIdx.x;
  const int bh = blockIdx.x >> 5, st = blockIdx.x & 31;
  const int b = bh >> 4, h = bh & 15;
  int r = tid >> 2, c0 = (tid & 3) << 4;
  const unsigned short* src = v + (size_t)(b*S_LEN + st*64 + r)*QKV_LD + h*64 + c0;
  *(us8*)&tile[r][c0]   = *(const us8*)&src[0];
  *(us8*)&tile[r][c0+8] = *(const us8*)&src[8];
  __syncthreads();
  int d = tid >> 2, s0 = (tid & 3) << 4;
  us8 o0, o1;
  #pragma unroll
  for (int j = 0; j < 8; j++) { o0[j] = tile[s0+j][d]; o1[j] = tile[s0+8+j][d]; }
  unsigned short* dst = vt + (size_t)(bh*64 + d)*S_LEN + st*64 + s0;
  *(us8*)&dst[0] = o0;
  *(us8*)&dst[8] = o1;
}

// ------- 256x256 pipelined GEMM (QKV / FFN1) -------
template<bool BIAS, bool GELU_>
__global__ __launch_bounds__(512, 2) void gemm256(
    const unsigned short* __restrict__ A, const unsigned short* __restrict__ Bt,
    unsigned short* __restrict__ Cout, const float* __restrict__ bias,
    int M, int N, int K)
{
  constexpr int BN = 256, WN = 64, NF = 4;
  __shared__ unsigned short sA[2][256*64];
  __shared__ unsigned short sB[2][BN*64];
  const int tid = threadIdx.x;
  const int wave = tid >> 6, lane = tid & 63;
  const int wm = wave >> 2, wn = wave & 3;
  const int l15 = lane & 15, g = lane >> 4, x7 = lane & 7, r8 = lane >> 3;
  const int srcc = (x7 ^ r8) << 3;
  const int nbn = N / BN;
  const int bid = xcd_swz(blockIdx.x, gridDim.x);
  const int bm = bid / nbn, bn = bid % nbn;
  const unsigned short* gA = A  + (size_t)(bm*256)*K;
  const unsigned short* gB = Bt + (size_t)(bn*BN)*K;
  const int NT = K >> 6;

  f32x4 acc[8][NF] = {};

#define STAGEA(buf, h, kb) do { \
    _Pragma("unroll") \
    for (int j_ = 0; j_ < 2; j_++) \
      GLD16(gA + (size_t)((h)*128 + j_*64 + wave*8 + r8)*K + (kb) + srcc, \
            &sA[buf][((h)*128 + j_*64 + wave*8)*64]); \
  } while (0)
#define STAGEB(buf, h, kb) do { \
    _Pragma("unroll") \
    for (int j_ = 0; j_ < 2; j_++) \
      GLD16(gB + (size_t)((h)*128 + j_*64 + wave*8 + r8)*K + (kb) + srcc, \
            &sB[buf][((h)*128 + j_*64 + wave*8)*64]); \
  } while (0)
#define RDA_(m, kk) (*(const bf16x8*)&cA[(wm*128 + (m)*16 + l15)*64 + ((((kk)*4+g)^x7)<<3)])
#define RDB_(n, kk) (*(const bf16x8*)&cB[(wn*WN + (n)*16 + l15)*64 + ((((kk)*4+g)^x7)<<3)])
#define PH(p) do { \
    __builtin_amdgcn_s_setprio(1); \
    _Pragma("unroll") for (int mm_ = 0; mm_ < 2; mm_++) \
    _Pragma("unroll") for (int n_ = 0; n_ < NF; n_++) \
    _Pragma("unroll") for (int kk_ = 0; kk_ < 2; kk_++) \
      acc[(p)*2+mm_][n_] = __builtin_amdgcn_mfma_f32_16x16x32_bf16( \
          af[mm_][kk_], bfr[n_][kk_], acc[(p)*2+mm_][n_], 0, 0, 0); \
    __builtin_amdgcn_s_setprio(0); \
  } while (0)

  // prologue: B(0),A(0) -> buf0 ; B(1) -> buf1
  STAGEB(0, 0, 0); STAGEB(0, 1, 0);
  STAGEA(0, 0, 0); STAGEA(0, 1, 0);
  STAGEB(1, 0, 64); STAGEB(1, 1, 64);

  for (int t = 0; t < NT; ++t) {
    const int c = t & 1;
    const unsigned short* cA = sA[c];
    const unsigned short* cB = sB[c];
    const int kb1 = (t + 1) * 64, kb2 = (t + 2) * 64;
    bf16x8 af[2][2], bfr[NF][2];

    if (t < NT - 1) asm volatile("s_waitcnt vmcnt(4)" ::: "memory");
    else            asm volatile("s_waitcnt vmcnt(0)" ::: "memory");
    __builtin_amdgcn_s_barrier();
    __builtin_amdgcn_sched_barrier(0);

    // ---- ph1: B reg-cache + A m0,m1 ----
    #pragma unroll
    for (int n = 0; n < NF; n++) { bfr[n][0] = RDB_(n, 0); bfr[n][1] = RDB_(n, 1); }
    af[0][0] = RDA_(0, 0); af[0][1] = RDA_(0, 1);
    af[1][0] = RDA_(1, 0); af[1][1] = RDA_(1, 1);
    if (t + 1 < NT) STAGEA(c ^ 1, 0, kb1);
    PH(0);
    // ---- ph2 ----
    af[0][0] = RDA_(2, 0); af[0][1] = RDA_(2, 1);
    af[1][0] = RDA_(3, 0); af[1][1] = RDA_(3, 1);
    if (t + 1 < NT) STAGEA(c ^ 1, 1, kb1);
    PH(1);
    __builtin_amdgcn_s_barrier();        // B-region recycle gate
    // ---- ph3 ----
    af[0][0] = RDA_(4, 0); af[0][1] = RDA_(4, 1);
    af[1][0] = RDA_(5, 0); af[1][1] = RDA_(5, 1);
    if (t + 2 < NT) STAGEB(c, 0, kb2);
    PH(2);
    // ---- ph4 ----
    af[0][0] = RDA_(6, 0); af[0][1] = RDA_(6, 1);
    af[1][0] = RDA_(7, 0); af[1][1] = RDA_(7, 1);
    if (t + 2 < NT) STAGEB(c, 1, kb2);
    PH(3);
  }

  // epilogue
  #pragma unroll
  for (int m = 0; m < 8; m++) {
    #pragma unroll
    for (int r = 0; r < 4; r++) {
      int grow = bm*256 + wm*128 + m*16 + g*4 + r;
      #pragma unroll
      for (int n = 0; n < NF; n++) {
        int gcol = bn*BN + wn*WN + n*16 + l15;
        float v = acc[m][n][r];
        if (BIAS) v += bias[gcol];
        if (GELU_) {
          float xx = v;
          float u = 0.7978845608f*(xx + 0.044715f*xx*xx*xx);
          float e = EXP2(u * 2.88539008f);
          float th = 1.0f - 2.0f*RCP(e + 1.0f);
          v = 0.5f*xx*(1.0f + th);
        }
        Cout[(size_t)grow*N + gcol] = f2bf(v);
      }
    }
  }
#undef STAGEA
#undef STAGEB
#undef RDA_
#undef RDB_
#undef PH
}

// ------- 128x256 pipelined GEMM (Wo / FFN2): 8 waves, per-wave 64x64 -------
// LDS: A 2x128x64 + B 2x256x64 (bf16) = 96KB -> 1 block/CU; grid = (M/128)x(N/256).
// Per K-tile: {vmcnt(4); barrier; ph1[B-regcache + A m0,m1 + stageA(t+1) + 16 MFMA];
//              barrier(B-recycle); ph2[A m2,m3 + stageB(t+2) + 16 MFMA]}.
template<bool BIAS, bool GELU_, bool RESID, bool OUTF32>
__global__ __launch_bounds__(512, 2) void gemm128(
    const unsigned short* __restrict__ A, const unsigned short* __restrict__ Bt,
    void* Cout, const float* __restrict__ bias, const float* resid,
    int M, int N, int K)
{
  __shared__ unsigned short sA[2][128*64];
  __shared__ unsigned short sB[2][256*64];
  const int tid = threadIdx.x;
  const int wave = tid >> 6, lane = tid & 63;
  const int wm = wave >> 2, wn = wave & 3;   // 2M x 4N waves
  const int l15 = lane & 15, g = lane >> 4, x7 = lane & 7, r8 = lane >> 3;
  const int srcc = (x7 ^ r8) << 3;
  const int nbn = N >> 8;
  const int bid = xcd_swz(blockIdx.x, gridDim.x);
  const int bm = bid / nbn, bn = bid % nbn;
  const unsigned short* gA = A  + (size_t)(bm*128)*K;
  const unsigned short* gB = Bt + (size_t)(bn*256)*K;
  const int NT = K >> 6;

  f32x4 acc[4][4] = {};

#define STAGEA1(buf, kb) do { \
    _Pragma("unroll") \
    for (int j_ = 0; j_ < 2; j_++) \
      GLD16(gA + (size_t)(j_*64 + wave*8 + r8)*K + (kb) + srcc, \
            &sA[buf][(j_*64 + wave*8)*64]); \
  } while (0)
#define STAGEB1(buf, kb) do { \
    _Pragma("unroll") \
    for (int j_ = 0; j_ < 4; j_++) \
      GLD16(gB + (size_t)(j_*64 + wave*8 + r8)*K + (kb) + srcc, \
            &sB[buf][(j_*64 + wave*8)*64]); \
  } while (0)
#define RDA1(m, kk) (*(const bf16x8*)&cA[(wm*64 + (m)*16 + l15)*64 + ((((kk)*4+g)^x7)<<3)])
#define RDB1(n, kk) (*(const bf16x8*)&cB[(wn*64 + (n)*16 + l15)*64 + ((((kk)*4+g)^x7)<<3)])
#define PH1(p) do { \
    __builtin_amdgcn_s_setprio(1); \
    _Pragma("unroll") for (int mm_ = 0; mm_ < 2; mm_++) \
    _Pragma("unroll") for (int n_ = 0; n_ < 4; n_++) \
    _Pragma("unroll") for (int kk_ = 0; kk_ < 2; kk_++) \
      acc[(p)*2+mm_][n_] = __builtin_amdgcn_mfma_f32_16x16x32_bf16( \
          af[mm_][kk_], bfr[n_][kk_], acc[(p)*2+mm_][n_], 0, 0, 0); \
    __builtin_amdgcn_s_setprio(0); \
  } while (0)

  // prologue: B(0) 4, A(0) 2, B(1) 4 loads/thread
  STAGEB1(0, 0);
  STAGEA1(0, 0);
  STAGEB1(1, 64);

  for (int t = 0; t < NT; ++t) {
    const int c = t & 1;
    const unsigned short* cA = sA[c];
    const unsigned short* cB = sB[c];
    const int kb1 = (t + 1) * 64, kb2 = (t + 2) * 64;
    bf16x8 af[2][2], bfr[4][2];

    // steady state: B(t+1)'s 4 loads in flight beyond A(t)/B(t)
    if (t < NT - 1) asm volatile("s_waitcnt vmcnt(4)" ::: "memory");
    else            asm volatile("s_waitcnt vmcnt(0)" ::: "memory");
    __builtin_amdgcn_s_barrier();
    __builtin_amdgcn_sched_barrier(0);

    // ---- ph1: B reg-cache + A m0,m1 + stage A(t+1) ----
    #pragma unroll
    for (int n = 0; n < 4; n++) { bfr[n][0] = RDB1(n, 0); bfr[n][1] = RDB1(n, 1); }
    af[0][0] = RDA1(0, 0); af[0][1] = RDA1(0, 1);
    af[1][0] = RDA1(1, 0); af[1][1] = RDA1(1, 1);
    if (t + 1 < NT) STAGEA1(c ^ 1, kb1);
    PH1(0);
    __builtin_amdgcn_s_barrier();        // B-region recycle gate (B reads done)
    // ---- ph2: A m2,m3 + stage B(t+2) into current buf ----
    af[0][0] = RDA1(2, 0); af[0][1] = RDA1(2, 1);
    af[1][0] = RDA1(3, 0); af[1][1] = RDA1(3, 1);
    if (t + 2 < NT) STAGEB1(c, kb2);
    PH1(1);
  }

  // epilogue: row = bm*128 + wm*64 + m*16 + g*4 + r ; col = bn*256 + wn*64 + n*16 + l15
  #pragma unroll
  for (int m = 0; m < 4; m++) {
    #pragma unroll
    for (int r = 0; r < 4; r++) {
      int grow = bm*128 + wm*64 + m*16 + g*4 + r;
      #pragma unroll
      for (int n = 0; n < 4; n++) {
        int gcol = bn*256 + wn*64 + n*16 + l15;
        float v = acc[m][n][r];
        if (BIAS) v += bias[gcol];
        if (GELU_) {
          float xx = v;
          float u = 0.7978845608f*(xx + 0.044715f*xx*xx*xx);
          float e = EXP2(u * 2.88539008f);
          float th = 1.0f - 2.0f*RCP(e + 1.0f);
          v = 0.5f*xx*(1.0f + th);
        }
        if (RESID) v += resid[(size_t)grow*N + gcol];
        if (OUTF32) ((float*)Cout)[(size_t)grow*N + gcol] = v;
        else ((unsigned short*)Cout)[(size_t)grow*N + gcol] = f2bf(v);
      }
    }
  }
#undef STAGEA1
#undef STAGEB1
#undef RDA1
#undef RDB1
#undef PH1
}

// ---------------- causal flash attention ----------------
// 8 waves / QBLK=128. Ones-column MFMA computes softmax denominator (no sum
// shuffles); max-reduce deferred behind a per-lane ballot (T13). exp2 domain.
__global__ __launch_bounds__(512) void attn_kernel(
    const unsigned short* __restrict__ qb, const unsigned short* __restrict__ kb,
    const unsigned short* __restrict__ vt, unsigned short* __restrict__ ctx)
{
  __shared__ unsigned short sK[2][64*64];
  __shared__ unsigned short sV[2][64*64];
  __shared__ unsigned short sP[8][16*64];
  const int tid = threadIdx.x, wave = tid >> 6, lane = tid & 63;
  const int l15 = lane & 15, g = lane >> 4, x7 = lane & 7;
  const int qt = 15 - (blockIdx.x >> 6);      // heavy-first, QBLK=128
  const int bh = blockIdx.x & 63;
  const int b = bh >> 4, h = bh & 15;
  const int qrow = qt*128 + wave*16;
  const int NTI = 2*qt + 2;                   // KV tiles (64 each)

  bf16x8 qf[2];
  {
    const unsigned short* qr = qb + (size_t)(b*S_LEN + qrow + l15) * QKV_LD + h*64;
    qf[0] = *(const bf16x8*)&qr[g*8];
    qf[1] = *(const bf16x8*)&qr[32 + g*8];
  }

  // all-ones bf16 fragment for the denominator MFMA
  us8 ones_u;
  #pragma unroll
  for (int j = 0; j < 8; j++) ones_u[j] = 0x3F80;
  const bf16x8 ones8 = __builtin_bit_cast(bf16x8, ones_u);

  f32x4 oacc[4] = {};
  f32x4 lacc = {};
  float mrow[4];
  #pragma unroll
  for (int r = 0; r < 4; r++) mrow[r] = -INFINITY;

  const int rrow = lane >> 3;
  const int srcc = (x7 ^ rrow) << 3;
  const unsigned short* kbase = kb + (size_t)(b*S_LEN)*QKV_LD + h*64 + srcc;
  const unsigned short* vbase = vt + (size_t)(bh*64)*S_LEN + srcc;

#define ASTAGE(buf, t) do { \
    const int kv0_ = (t)*64; \
    GLD16(kbase + (size_t)(kv0_ + wave*8 + rrow)*QKV_LD, &sK[buf][wave*8*64]); \
    GLD16(vbase + (size_t)(wave*8 + rrow)*S_LEN + kv0_,  &sV[buf][wave*8*64]); \
  } while(0)

  ASTAGE(0, 0);

  for (int t = 0; t < NTI; ++t) {
    __syncthreads();
    const int cur = t & 1;
    if (t < NTI - 1) ASTAGE(cur ^ 1, t + 1);

    const int kv0 = t*64;
    if (kv0 > qrow + 15) continue;   // fully-masked tile for this wave

    f32x4 sacc[4] = {};
    __builtin_amdgcn_s_setprio(1);
    #pragma unroll
    for (int kk = 0; kk < 2; kk++) {
      const int csw = ((kk*4 + g) ^ x7) << 3;
      #pragma unroll
      for (int n = 0; n < 4; n++) {
        bf16x8 kf = *(const bf16x8*)&sK[cur][(n*16 + l15)*64 + csw];
        sacc[n] = __builtin_amdgcn_mfma_f32_16x16x32_bf16(qf[kk], kf, sacc[n], 0, 0, 0);
      }
    }
    __builtin_amdgcn_s_setprio(0);

    float p[4][4], rm[4];
    const bool masked = (kv0 + 63 > qrow);
    #pragma unroll
    for (int r = 0; r < 4; r++) {
      float m_ = -INFINITY;
      #pragma unroll
      for (int n = 0; n < 4; n++) {
        float sc = sacc[n][r];     // already log2-scaled via Wq
        if (masked && (kv0 + n*16 + l15) > (qrow + g*4 + r)) sc = -INFINITY;
        p[n][r] = sc;
        m_ = fmaxf(m_, sc);
      }
      rm[r] = m_;
    }
    // defer-max: full 16-lane reduce + rescale only when a lane max exceeds
    bool need = (rm[0] > mrow[0] + 8.0f) | (rm[1] > mrow[1] + 8.0f) |
                (rm[2] > mrow[2] + 8.0f) | (rm[3] > mrow[3] + 8.0f);
    if (__any(need)) {
      #pragma unroll
      for (int r = 0; r < 4; r++) {
        float vv = rm[r];
        vv = fmaxf(vv, __shfl_xor(vv, 1));
        vv = fmaxf(vv, __shfl_xor(vv, 2));
        vv = fmaxf(vv, __shfl_xor(vv, 4));
        vv = fmaxf(vv, __shfl_xor(vv, 8));
        float mn = fmaxf(mrow[r], vv);
        float alpha = EXP2(mrow[r] - mn);
        mrow[r] = mn;
        lacc[r] *= alpha;
        #pragma unroll
        for (int nd = 0; nd < 4; nd++) oacc[nd][r] *= alpha;
      }
    }
    #pragma unroll
    for (int n = 0; n < 4; n++)
      #pragma unroll
      for (int r = 0; r < 4; r++)
        p[n][r] = EXP2(p[n][r] - mrow[r]);

    #pragma unroll
    for (int n = 0; n < 4; n++) {
      const int chunk = n*2 + (l15 >> 3);
      #pragma unroll
      for (int r = 0; r < 4; r++) {
        const int prow = g*4 + r;
        sP[wave][prow*64 + ((chunk ^ (prow & 7)) << 3) + x7] = f2bf(p[n][r]);
      }
    }
    asm volatile("s_waitcnt lgkmcnt(0)" ::: "memory");
    __builtin_amdgcn_sched_barrier(0);

    __builtin_amdgcn_s_setprio(1);
    #pragma unroll
    for (int kk = 0; kk < 2; kk++) {
      const int csw = ((kk*4 + g) ^ x7) << 3;
      bf16x8 pa = *(const bf16x8*)&sP[wave][l15*64 + csw];
      #pragma unroll
      for (int nd = 0; nd < 4; nd++) {
        bf16x8 vf = *(const bf16x8*)&sV[cur][(nd*16 + l15)*64 + csw];
        oacc[nd] = __builtin_amdgcn_mfma_f32_16x16x32_bf16(pa, vf, oacc[nd], 0, 0, 0);
      }
      lacc = __builtin_amdgcn_mfma_f32_16x16x32_bf16(pa, ones8, lacc, 0, 0, 0);
    }
    __builtin_amdgcn_s_setprio(0);
  }

  #pragma unroll
  for (int r = 0; r < 4; r++) {
    float inv = RCP(lacc[r]);
    size_t row = (size_t)(b*S_LEN + qrow + g*4 + r);
    #pragma unroll
    for (int nd = 0; nd < 4; nd++)
      ctx[row*DMODEL + h*64 + nd*16 + l15] = f2bf(oacc[nd][r] * inv);
  }
}

// ---------------- host ----------------
extern "C" void kernel_launch(void* const* d_in, const int* in_sizes, int n_in,
                              void* d_out, int out_size, void* d_ws, size_t ws_size,
                              hipStream_t stream)
{
  const float* x    = (const float*)d_in[0];
  const float* Wq   = (const float*)d_in[1];
  const float* Wk   = (const float*)d_in[2];
  const float* Wv   = (const float*)d_in[3];
  const float* Wo   = (const float*)d_in[4];
  const float* bo   = (const float*)d_in[5];
  const float* W1   = (const float*)d_in[6];
  const float* b1   = (const float*)d_in[7];
  const float* W2   = (const float*)d_in[8];
  const float* b2   = (const float*)d_in[9];
  const float* ln1s = (const float*)d_in[10];
  const float* ln1b = (const float*)d_in[11];
  const float* ln2s = (const float*)d_in[12];
  const float* ln2b = (const float*)d_in[13];
  float* out = (float*)d_out;
  (void)in_sizes; (void)n_in; (void)out_size; (void)ws_size;

  char* ws = (char*)d_ws;
  size_t off = 0;
  auto alloc = [&](size_t n) { char* p = ws + off; off += (n + 255) & ~(size_t)255; return p; };
  unsigned short* hbuf  = (unsigned short*)alloc((size_t)NROWS*DMODEL*2);
  unsigned short* qkv   = (unsigned short*)alloc((size_t)NROWS*QKV_LD*2);
  unsigned short* vtb   = (unsigned short*)alloc((size_t)NROWS*DMODEL*2);
  unsigned short* ctx   = (unsigned short*)alloc((size_t)NROWS*DMODEL*2);
  unsigned short* ffn1  = (unsigned short*)alloc((size_t)NROWS*DFF*2);
  unsigned short* wqkvt = (unsigned short*)alloc((size_t)QKV_LD*DMODEL*2);
  unsigned short* wot   = (unsigned short*)alloc((size_t)DMODEL*DMODEL*2);
  unsigned short* w1t   = (unsigned short*)alloc((size_t)DFF*DMODEL*2);
  unsigned short* w2t   = (unsigned short*)alloc((size_t)DMODEL*DFF*2);

  const float SCLQ = 0.18033688011f;  // log2(e)/sqrt(64)

  wtrans_all<<<dim3(3072), dim3(256), 0, stream>>>(
      Wq, Wk, Wv, Wo, W1, W2, wqkvt, wot, w1t, w2t, SCLQ);

  // LN1
  ln_kernel<<<dim3(NROWS), dim3(256), 0, stream>>>(x, ln1s, ln1b, hbuf);
  // fused QKV projection (256x256 pipelined)
  gemm256<false,false><<<dim3(32*12), dim3(512), 0, stream>>>(
      hbuf, wqkvt, qkv, nullptr, NROWS, QKV_LD, DMODEL);
  // V^T
  vtrans<<<dim3(2048), dim3(256), 0, stream>>>(qkv + 2048, vtb);
  // attention (8-wave, QBLK=128)
  attn_kernel<<<dim3(1024), dim3(512), 0, stream>>>(qkv, qkv + 1024, vtb, ctx);
  // out proj + bo + residual(x) -> d_out fp32  (128x256 pipelined, 256 blocks)
  gemm128<true,false,true,true><<<dim3(64*4), dim3(512), 0, stream>>>(
      ctx, wot, (void*)out, bo, x, NROWS, DMODEL, DMODEL);
  // LN2
  ln_kernel<<<dim3(NROWS), dim3(256), 0, stream>>>(out, ln2s, ln2b, hbuf);
  // FFN1 + b1 + GELU -> bf16 (256x256 pipelined)
  gemm256<true,true><<<dim3(32*16), dim3(512), 0, stream>>>(
      hbuf, w1t, ffn1, b1, NROWS, DFF, DMODEL);
  // FFN2 + b2 + residual(d_out) -> d_out fp32  (128x256 pipelined, 256 blocks)
  gemm128<true,false,true,true><<<dim3(64*4), dim3(512), 0, stream>>>(
      ffn1, w2t, (void*)out, b2, out, NROWS, DMODEL, DFF);
}